// Round 7
// baseline (2151.885 us; speedup 1.0000x reference)
//
#include <hip/hip_runtime.h>

typedef unsigned short u16;
typedef unsigned int u32;
typedef __attribute__((ext_vector_type(8))) short short8;
typedef __attribute__((ext_vector_type(4))) float floatx4;

__device__ __forceinline__ float bf2f(u16 u) {
    union { unsigned int i; float f; } v; v.i = ((unsigned int)u) << 16; return v.f;
}
__device__ __forceinline__ u16 f2bf(float f) {
    union { float f; unsigned int i; } v; v.f = f;
    unsigned int i = v.i + 0x7fffu + ((v.i >> 16) & 1u);  // RNE
    return (u16)(i >> 16);
}

// async global->LDS, 16B per lane; LDS dest must be wave-uniform base + lane*16
#define GLL(g, l) __builtin_amdgcn_global_load_lds( \
    (const __attribute__((address_space(1))) void*)(g), \
    (__attribute__((address_space(3))) void*)(l), 16, 0, 0)

// Ha halo tensor: [b][f_idx 0..65][t_idx 0..513 (pad 514)][ci 0..31] bf16
#define HA_BSTRIDE 1085568  // 66*514*32

// ---------------- dtype sniffer: flag=1 means inputs are float32 ----------------
__global__ __launch_bounds__(256) void sniff_k(const u16* __restrict__ x, int* __restrict__ flag) {
    __shared__ int red[4];
    int cnt = 0;
    for (int i = 0; i < 16; ++i) {
        u16 v = x[(threadIdx.x * 16 + i) * 2];
        int e = (v >> 7) & 0xFF;
        if (e >= 110 && e <= 135) cnt++;
    }
    #pragma unroll
    for (int off = 32; off; off >>= 1) cnt += __shfl_down(cnt, off);
    if ((threadIdx.x & 63) == 0) red[threadIdx.x >> 6] = cnt;
    __syncthreads();
    if (threadIdx.x == 0) {
        int tot = red[0] + red[1] + red[2] + red[3];
        *flag = (tot < 2048) ? 1 : 0;
    }
}

__device__ __forceinline__ float ldin(const void* p, size_t i, int isf32) {
    return isf32 ? ((const float*)p)[i] : bf2f(((const u16*)p)[i]);
}

// ---------------- canonicalize all params to f32 park (one launch) ----------------
struct CvtArgs {
    const void* src[19];
    int len[19];
    int off[19];
};
__global__ __launch_bounds__(256) void cvtall_k(CvtArgs a, float* __restrict__ dst,
                                                const int* __restrict__ flag) {
    int isf32 = *flag;
    int seg = blockIdx.y;
    int n = a.len[seg];
    const void* s = a.src[seg];
    float* d = dst + a.off[seg];
    for (int i = blockIdx.x * 256 + threadIdx.x; i < n; i += gridDim.x * 256)
        d[i] = ldin(s, i, isf32);
}

// ---------------- weight transpose: W[K][N] (dual dtype) -> Wt[N][K] bf16 ----------------
__global__ __launch_bounds__(256) void wtr_k(const void* __restrict__ W, int ldw, size_t wofs,
                                             u16* __restrict__ Wt, int ldt,
                                             const int* __restrict__ flag) {
    int isf32 = *flag;
    __shared__ u16 t[64][65];
    int k0 = blockIdx.x * 64, n0 = blockIdx.y * 64;
    int tid = threadIdx.x;
    #pragma unroll
    for (int i = 0; i < 16; ++i) {
        int kk = i * 4 + (tid >> 6), nn = tid & 63;
        t[kk][nn] = f2bf(ldin(W, wofs + (size_t)(k0 + kk) * ldw + n0 + nn, isf32));
    }
    __syncthreads();
    #pragma unroll
    for (int i = 0; i < 16; ++i) {
        int nn = i * 4 + (tid >> 6), kk = tid & 63;
        Wt[(size_t)(n0 + nn) * ldt + k0 + kk] = t[kk][nn];
    }
}

// ---------------- zero / guard fill ----------------
__global__ __launch_bounds__(256) void zero_k(float4* __restrict__ p, int n4) {
    float4 z = {0.f, 0.f, 0.f, 0.f};
    for (int i = blockIdx.x * 256 + threadIdx.x; i < n4; i += gridDim.x * 256) p[i] = z;
}
__global__ __launch_bounds__(256) void fill_k(float* __restrict__ p, int n) {
    int i = blockIdx.x * 256 + threadIdx.x;
    if (i < n) p[i] = 1.0e6f;
}

// ---------------- conv stem: 1->32, k3 s2 p1 -> X f32 NCHW; 4 outputs/thread ----------------
__global__ __launch_bounds__(256) void conv1_k(const void* __restrict__ x, const float* __restrict__ w,
                                               const float* __restrict__ bias, float* __restrict__ out,
                                               const int* __restrict__ flag) {
    int isf32 = *flag;
    int idx = blockIdx.x * 256 + threadIdx.x;   // 2^22 threads
    int t4 = idx & 127;          // output t block: t = 4*t4 + o
    int f  = (idx >> 7) & 63;
    int co = (idx >> 13) & 31;
    int b  = idx >> 18;
    size_t xb = (size_t)b * 128 * 1024;

    float wr[9];
    #pragma unroll
    for (int k = 0; k < 9; ++k) wr[k] = w[co * 9 + k];

    float bs = bias[co];
    float acc[4] = {bs, bs, bs, bs};
    int tbase = 8 * t4 - 1;
    #pragma unroll
    for (int df = 0; df < 3; ++df) {
        int fi = 2 * f + df - 1;
        if (fi < 0 || fi >= 128) continue;
        size_t rowb = xb + (size_t)fi * 1024;
        float xv[10];
        #pragma unroll
        for (int k = 0; k < 10; ++k) {
            int ti = tbase + k;
            int tc_ = min(max(ti, 0), 1023);
            float v = isf32 ? ((const float*)x)[rowb + tc_] : bf2f(((const u16*)x)[rowb + tc_]);
            xv[k] = (ti == tc_) ? v : 0.f;
        }
        #pragma unroll
        for (int dt = 0; dt < 3; ++dt)
            #pragma unroll
            for (int o = 0; o < 4; ++o)
                acc[o] = fmaf(wr[df * 3 + dt], xv[2 * o + dt], acc[o]);
    }
    float4 ov = {acc[0], acc[1], acc[2], acc[3]};
    *(float4*)(out + ((((size_t)b * 32 + co) * 64 + f) * 512 + 4 * t4)) = ov;
}

// ---------------- LN-over-f stats (dual-dtype input, NCHW) ----------------
__global__ __launch_bounds__(256) void stats_k(const void* __restrict__ X, int isbf,
                                               float* __restrict__ sm, float* __restrict__ sr) {
    int idx = blockIdx.x * 256 + threadIdx.x;  // 16*32*512
    int t  = idx & 511;
    int bc = idx >> 9;
    size_t base = (size_t)bc * 64 * 512 + t;
    float s = 0.f, s2 = 0.f;
    #pragma unroll 8
    for (int f = 0; f < 64; ++f) {
        float v = isbf ? bf2f(((const u16*)X)[base + f * 512]) : ((const float*)X)[base + f * 512];
        s += v; s2 += v * v;
    }
    float m  = s * (1.f / 64.f);
    float var = fmaxf(s2 * (1.f / 64.f) - m * m, 0.f);
    sm[idx] = m;
    sr[idx] = rsqrtf(var + 1e-5f);
}

// ---------------- apply LN+ReLU: NCHW (f32|bf16) -> Ha NHWC halo bf16 ----------------
__global__ __launch_bounds__(256) void apply_k(const void* __restrict__ in, int isbf,
                                               const float* __restrict__ sm, const float* __restrict__ sr,
                                               const float* __restrict__ g, const float* __restrict__ be,
                                               u16* __restrict__ Ha) {
    int f = blockIdx.x;
    int b = blockIdx.y;
    float gg = g[f], bb_ = be[f];
    for (int it = 0; it < 2; ++it) {
        int t = it * 256 + threadIdx.x;
        u32 pk[16];
        #pragma unroll
        for (int cp = 0; cp < 16; ++cp) {
            u32 w = 0;
            #pragma unroll
            for (int half = 0; half < 2; ++half) {
                int ci = cp * 2 + half;
                size_t xi = (((size_t)b * 32 + ci) * 64 + f) * 512 + t;
                float xv = isbf ? bf2f(((const u16*)in)[xi]) : ((const float*)in)[xi];
                int si = (b * 32 + ci) * 512 + t;
                float hv = fmaxf((xv - sm[si]) * sr[si] * gg + bb_, 0.f);
                w |= ((u32)f2bf(hv)) << (half * 16);
            }
            pk[cp] = w;
        }
        u32* orow = (u32*)(Ha + (size_t)b * HA_BSTRIDE + ((size_t)(f + 1) * 514 + (t + 1)) * 32);
        #pragma unroll
        for (int q = 0; q < 16; ++q) orow[q] = pk[q];
    }
}

// ---------------- conv32 k3 s1 p1 via MFMA, GLL staging from Ha ----------------
__global__ __launch_bounds__(256) void convm_k(const u16* __restrict__ Ha, void* __restrict__ out,
                                               const float* __restrict__ w, const float* __restrict__ bias,
                                               const float* __restrict__ res) {
    __shared__ u16 act[6 * 66 * 32];  // 25344 B
    int f0 = blockIdx.x * 4;
    int t0 = blockIdx.y * 64;
    int b  = blockIdx.z;
    const u16* Hb = Ha + (size_t)b * HA_BSTRIDE;

    int lane = threadIdx.x & 63;
    int wv   = threadIdx.x >> 6;
    int quad = lane >> 4;
    int r    = lane & 15;

    for (int u = threadIdx.x; u < 1584; u += 256) {
        int fp  = u / 264;
        int rem = u - fp * 264;
        int tp  = rem >> 2;
        int q   = rem & 3;
        const u16* gp = Hb + ((size_t)(f0 + fp) * 514 + (t0 + tp)) * 32 + q * 8;
        GLL(gp, act + u * 8);
    }

    short8 bfrag[3][3][2];
    #pragma unroll
    for (int df = 0; df < 3; ++df)
        #pragma unroll
        for (int dt = 0; dt < 3; ++dt)
            #pragma unroll
            for (int ct = 0; ct < 2; ++ct) {
                short8 v;
                #pragma unroll
                for (int j = 0; j < 8; ++j) {
                    int co = ct * 16 + r, ci = quad * 8 + j;
                    v[j] = (short)f2bf(w[(co * 32 + ci) * 9 + df * 3 + dt]);
                }
                bfrag[df][dt][ct] = v;
            }
    __syncthreads();

    floatx4 acc[4][2];
    #pragma unroll
    for (int i = 0; i < 4; ++i)
        #pragma unroll
        for (int j = 0; j < 2; ++j)
            #pragma unroll
            for (int k = 0; k < 4; ++k) acc[i][j][k] = 0.f;

    int tw = wv * 16;
    #pragma unroll
    for (int fh = 0; fh < 6; ++fh) {
        short8 af[3];
        #pragma unroll
        for (int dt = 0; dt < 3; ++dt)
            af[dt] = *(const short8*)&act[((fh * 66) + tw + r + dt) * 32 + quad * 8];
        #pragma unroll
        for (int df = 0; df < 3; ++df) {
            int rel = fh - df;
            if (rel < 0 || rel >= 4) continue;
            #pragma unroll
            for (int dt = 0; dt < 3; ++dt)
                #pragma unroll
                for (int ct = 0; ct < 2; ++ct)
                    acc[rel][ct] = __builtin_amdgcn_mfma_f32_16x16x32_bf16(
                        af[dt], bfrag[df][dt][ct], acc[rel][ct], 0, 0, 0);
        }
    }

    int tt = t0 + tw + quad * 4;
    #pragma unroll
    for (int rel = 0; rel < 4; ++rel)
        #pragma unroll
        for (int ct = 0; ct < 2; ++ct) {
            int f  = f0 + rel;
            int co = ct * 16 + r;
            size_t base = (((size_t)b * 32 + co) * 64 + f) * 512 + tt;
            float bs = bias[co];
            if (res) {
                float4 rv = *(const float4*)(res + base);
                float4 o;
                o.x = acc[rel][ct][0] + bs + rv.x;
                o.y = acc[rel][ct][1] + bs + rv.y;
                o.z = acc[rel][ct][2] + bs + rv.z;
                o.w = acc[rel][ct][3] + bs + rv.w;
                *(float4*)((float*)out + base) = o;
            } else {
                ushort4 o;
                o.x = f2bf(acc[rel][ct][0] + bs);
                o.y = f2bf(acc[rel][ct][1] + bs);
                o.z = f2bf(acc[rel][ct][2] + bs);
                o.w = f2bf(acc[rel][ct][3] + bs);
                *(ushort4*)((u16*)out + base) = o;
            }
        }
}

// ---------------- transpose X (b,c,f,t) f32 -> A[(t*16+b)][(c*64+f)] bf16 ----------------
__global__ __launch_bounds__(256) void transpose_k(const float* __restrict__ X, u16* __restrict__ A) {
    __shared__ float tile[64][65];
    int t0 = blockIdx.x * 64;
    int c  = blockIdx.y;
    int b  = blockIdx.z;
    const float* p = X + (((size_t)b * 32 + c) * 64) * 512 + t0;
    #pragma unroll
    for (int i = 0; i < 16; ++i) {
        int f = i * 4 + (threadIdx.x >> 6);
        int t = threadIdx.x & 63;
        tile[f][t] = p[(size_t)f * 512 + t];
    }
    __syncthreads();
    #pragma unroll
    for (int i = 0; i < 16; ++i) {
        int t = i * 4 + (threadIdx.x >> 6);
        int f = threadIdx.x & 63;
        A[((size_t)(t0 + t) * 16 + b) * 2048 + c * 64 + f] = f2bf(tile[f][t]);
    }
}

// ---------------- row layernorm, f32 in -> bf16 out ----------------
__global__ __launch_bounds__(256) void lnlast_k(const float* __restrict__ X, u16* __restrict__ Y,
                                                const float* __restrict__ g, const float* __restrict__ bt,
                                                int width) {
    int row = blockIdx.x;
    const float* p = X + (size_t)row * width;
    float s = 0.f, s2 = 0.f;
    for (int i = threadIdx.x; i < width; i += 256) { float v = p[i]; s += v; s2 += v * v; }
    #pragma unroll
    for (int off = 32; off; off >>= 1) { s += __shfl_down(s, off); s2 += __shfl_down(s2, off); }
    __shared__ float red[4][2];
    int wv = threadIdx.x >> 6;
    if ((threadIdx.x & 63) == 0) { red[wv][0] = s; red[wv][1] = s2; }
    __syncthreads();
    if (threadIdx.x == 0) {
        float a = 0.f, b2 = 0.f;
        for (int i = 0; i < 4; ++i) { a += red[i][0]; b2 += red[i][1]; }
        float m = a / width;
        float var = fmaxf(b2 / width - m * m, 0.f);
        red[0][0] = m; red[0][1] = rsqrtf(var + 1e-5f);
    }
    __syncthreads();
    float m = red[0][0], rs = red[0][1];
    u16* q = Y + (size_t)row * width;
    for (int i = threadIdx.x; i < width; i += 256)
        q[i] = f2bf((p[i] - m) * rs * g[i] + bt[i]);
}

// ---------------- m97-style MFMA GEMM: C = A @ Bt^T, 128x128, BK=32, GLL staging ----------
__global__ __launch_bounds__(256) void gemm_bt(const u16* __restrict__ A, const u16* __restrict__ A2,
                                               int lda, const u16* __restrict__ Bt, int ldb,
                                               void* __restrict__ C, void* __restrict__ C2,
                                               int ldc, int nsplit,
                                               const float* __restrict__ bias, int relu, int K,
                                               int obf) {
    __shared__ u16 As[128 * 32];
    __shared__ u16 Bs[128 * 32];
    int tid  = threadIdx.x;
    int bm   = blockIdx.x * 128;
    int bn   = blockIdx.y * 128;
    const u16* Ab = A;
    void* Cb = C;
    int cn = bn;
    if (bn >= nsplit) { Ab = A2; Cb = C2; cn = bn - nsplit; }

    int lane = tid & 63;
    int wv   = tid >> 6;
    int quad = lane >> 4;
    int r    = lane & 15;
    int wm   = (wv >> 1) * 64;
    int wn   = (wv & 1) * 64;

    floatx4 acc[4][4];
    #pragma unroll
    for (int i = 0; i < 4; ++i)
        #pragma unroll
        for (int j = 0; j < 4; ++j)
            #pragma unroll
            for (int k = 0; k < 4; ++k) acc[i][j][k] = 0.f;

    int row0 = tid >> 2;
    int ks0  = (tid & 3) * 8;
    const u16* Abase  = Ab + (size_t)(bm + row0) * lda + ks0;
    const u16* Abase2 = Ab + (size_t)(bm + 64 + row0) * lda + ks0;
    const u16* Bbase  = Bt + (size_t)(bn + row0) * ldb + ks0;
    const u16* Bbase2 = Bt + (size_t)(bn + 64 + row0) * ldb + ks0;
    u16* AsD  = As + tid * 8;
    u16* AsD2 = As + 2048 + tid * 8;
    u16* BsD  = Bs + tid * 8;
    u16* BsD2 = Bs + 2048 + tid * 8;

    for (int k0 = 0; k0 < K; k0 += 32) {
        GLL(Abase + k0, AsD);
        GLL(Abase2 + k0, AsD2);
        GLL(Bbase + k0, BsD);
        GLL(Bbase2 + k0, BsD2);
        __syncthreads();
        short8 af[4], bf[4];
        #pragma unroll
        for (int mi = 0; mi < 4; ++mi) af[mi] = *(const short8*)&As[(wm + mi * 16 + r) * 32 + quad * 8];
        #pragma unroll
        for (int ni = 0; ni < 4; ++ni) bf[ni] = *(const short8*)&Bs[(wn + ni * 16 + r) * 32 + quad * 8];
        #pragma unroll
        for (int mi = 0; mi < 4; ++mi)
            #pragma unroll
            for (int ni = 0; ni < 4; ++ni)
                acc[mi][ni] = __builtin_amdgcn_mfma_f32_16x16x32_bf16(af[mi], bf[ni], acc[mi][ni], 0, 0, 0);
        __syncthreads();
    }

    #pragma unroll
    for (int mi = 0; mi < 4; ++mi)
        #pragma unroll
        for (int ni = 0; ni < 4; ++ni) {
            int col = cn + wn + ni * 16 + r;
            float bs = bias ? bias[col] : 0.f;
            #pragma unroll
            for (int reg = 0; reg < 4; ++reg) {
                int row = bm + wm + mi * 16 + quad * 4 + reg;
                float v = acc[mi][ni][reg] + bs;
                if (relu) v = fmaxf(v, 0.f);
                if (obf) ((u16*)Cb)[(size_t)row * ldc + col] = f2bf(v);
                else     ((float*)Cb)[(size_t)row * ldc + col] = v;
            }
        }
}

// ---------------- SRU recurrence: depth-8 register-ring prefetch ----------------
#define TC 256
#define PD 8
__global__ __launch_bounds__(64) void scan_k(const u16* __restrict__ Uf, const u16* __restrict__ Ub,
                                             const float* __restrict__ Xp, float* __restrict__ Xn,
                                             float* __restrict__ cstate, const float* __restrict__ vv,
                                             const float* __restrict__ bb, int t0f, int t0b, int init) {
    int gid = blockIdx.x * 64 + threadIdx.x;  // 16384
    int d  = gid >> 13;
    int b  = (gid >> 9) & 15;
    int h  = gid & 511;
    float v0 = vv[(d * 2 + 0) * 512 + h];
    float v1 = vv[(d * 2 + 1) * 512 + h];
    float b0 = bb[(d * 2 + 0) * 512 + h];
    float b1 = bb[(d * 2 + 1) * 512 + h];
    const u16* u = (d ? Ub : Uf) + (size_t)b * 1536 + h;
    int t0 = d ? t0b : t0f;
    const float* xb = Xp + (size_t)b * 1024 + d * 512 + h;
    float*       ob = Xn + (size_t)b * 1024 + d * 512 + h;
    float c = init ? 0.f : cstate[gid];

    float pu0[PD], pfp[PD], prp[PD], pxr[PD];
    #pragma unroll
    for (int s = 0; s < PD; ++s) {
        int sl = d ? (TC - 1 - s) : s;
        size_t ro = (size_t)sl * 16 * 1536;
        pu0[s] = bf2f(u[ro]);
        pfp[s] = bf2f(u[ro + 512]);
        prp[s] = bf2f(u[ro + 1024]);
        pxr[s] = xb[(size_t)(t0 + sl) * 16 * 1024];
    }
    #pragma unroll 8
    for (int s = 0; s < TC; ++s) {
        int slot = s & (PD - 1);
        float u0 = pu0[slot], fp_ = pfp[slot], rp_ = prp[slot], xr = pxr[slot];
        int sp = s + PD;
        if (sp < TC) {
            int sl2 = d ? (TC - 1 - sp) : sp;
            size_t ro2 = (size_t)sl2 * 16 * 1536;
            pu0[slot] = bf2f(u[ro2]);
            pfp[slot] = bf2f(u[ro2 + 512]);
            prp[slot] = bf2f(u[ro2 + 1024]);
            pxr[slot] = xb[(size_t)(t0 + sl2) * 16 * 1024];
        }
        float f = 1.f / (1.f + __expf(-(fp_ + b0 + v0 * c)));
        float r = 1.f / (1.f + __expf(-(rp_ + b1 + v1 * c)));
        c = f * c + (1.f - f) * u0;
        float th = 1.f - 2.f / (__expf(2.f * c) + 1.f);
        int sl = d ? (TC - 1 - s) : s;
        ob[(size_t)(t0 + sl) * 16 * 1024] = r * th + (1.f - r) * xr;
    }
    cstate[gid] = c;
}

// ---------------- classifier head ----------------
__global__ __launch_bounds__(256) void cls2_k(const float* __restrict__ FC1, const float* __restrict__ W2,
                                              const float* __restrict__ b2, void* __restrict__ out,
                                              const int* __restrict__ flag) {
    int isf32 = *flag;
    int row = blockIdx.x * 4 + (threadIdx.x >> 6);
    int v   = threadIdx.x & 63;
    if (v >= 29) return;
    const float* p = FC1 + (size_t)row * 512;
    float acc = 0.f;
    for (int k = 0; k < 512; ++k) acc = fmaf(p[k], W2[k * 29 + v], acc);
    acc += b2[v];
    int t = row >> 4, b = row & 15;
    size_t oi = ((size_t)b * 512 + t) * 29 + v;
    if (isf32) ((float*)out)[oi] = acc;
    else       ((u16*)out)[oi]   = f2bf(acc);
}

// ---------------- launch ----------------
extern "C" void kernel_launch(void* const* d_in, const int* in_sizes, int n_in,
                              void* d_out, int out_size, void* d_ws, size_t ws_size,
                              hipStream_t stream) {
    const void* x      = d_in[0];
    const void* proj_w = d_in[11];
    const void* sru_w  = d_in[12];
    const void* cls_w1 = d_in[19];

    float* ws = (float*)d_ws;
    const size_t O_X    = 0;
    const size_t O_C    = 16777216;
    const size_t O_HA   = 25165824;
    const size_t O_SM   = 33850368;
    const size_t O_SR   = 34112512;
    const size_t O_CST  = 34374656;
    const size_t O_PARK = 34391040;
    const size_t O_FLAG = 34483488;
    const size_t TOTAL  = 34483504;   // 131.55 MiB
    if (ws_size < TOTAL * sizeof(float)) {
        fill_k<<<(out_size + 255) / 256, 256, 0, stream>>>((float*)d_out, out_size);
        return;
    }

    float* X   = ws + O_X;
    u16*   C   = (u16*)(ws + O_C);
    u16*   HA  = (u16*)(ws + O_HA);
    float* SM  = ws + O_SM;
    float* SR  = ws + O_SR;
    float* CST = ws + O_CST;
    float* PK  = ws + O_PARK;
    int*   FLG = (int*)(ws + O_FLAG);

    u16*   Abf = (u16*)(ws + O_C);
    u16*   BtP = (u16*)(ws + 0);
    float* XP0 = ws + 25165824;
    u16*   XL  = (u16*)(ws + 0);
    float* XP1 = ws + 4194304;
    u16*   Uf  = (u16*)(ws + 12582912);
    u16*   Ub  = (u16*)(ws + 15728640);
    u16*   BtS = (u16*)(ws + 18874368);
    u16*   BtC = (u16*)(ws + O_SM);
    float* FC1 = ws + 12582912;

    float* p_cnn_w = PK + 0;      float* p_cnn_b = PK + 288;
    float* p_rw1   = PK + 320;    float* p_rb1   = PK + 27968;
    float* p_rw2   = PK + 28064;  float* p_rb2   = PK + 55712;
    float* p_l1g   = PK + 55808;  float* p_l1b   = PK + 56000;
    float* p_l2g   = PK + 56192;  float* p_l2b   = PK + 56384;
    float* p_sv    = PK + 56576;  float* p_sb    = PK + 62720;
    float* p_slng  = PK + 68864;  float* p_slnb  = PK + 71936;
    float* p_clng  = PK + 75008;  float* p_clnb  = PK + 76032;
    float* p_cb1   = PK + 77056;  float* p_cw2   = PK + 77568;
    float* p_cb2   = PK + 92416;

    sniff_k<<<1, 256, 0, stream>>>((const u16*)x, FLG);

    CvtArgs ca;
    const int srcidx[19] = {1,2,3,4,5,6,7,8,9,10,13,14,15,16,17,18,20,21,22};
    const int lens[19]   = {288,32,27648,96,27648,96,192,192,192,192,6144,6144,3072,3072,1024,1024,512,14848,29};
    const int offs[19]   = {0,288,320,27968,28064,55712,55808,56000,56192,56384,56576,62720,68864,71936,75008,76032,77056,77568,92416};
    for (int i = 0; i < 19; ++i) { ca.src[i] = d_in[srcidx[i]]; ca.len[i] = lens[i]; ca.off[i] = offs[i]; }
    cvtall_k<<<dim3(108, 19), 256, 0, stream>>>(ca, PK, FLG);

    zero_k<<<2048, 256, 0, stream>>>((float4*)HA, 2171136);
    conv1_k<<<16384, 256, 0, stream>>>(x, p_cnn_w, p_cnn_b, X, FLG);

    for (int i = 0; i < 3; ++i) {
        stats_k<<<1024, 256, 0, stream>>>(X, 0, SM, SR);
        apply_k<<<dim3(64, 16), 256, 0, stream>>>(X, 0, SM, SR, p_l1g + i * 64, p_l1b + i * 64, HA);
        convm_k<<<dim3(16, 8, 16), 256, 0, stream>>>(HA, C, p_rw1 + i * 9216, p_rb1 + i * 32, nullptr);
        stats_k<<<1024, 256, 0, stream>>>(C, 1, SM, SR);
        apply_k<<<dim3(64, 16), 256, 0, stream>>>(C, 1, SM, SR, p_l2g + i * 64, p_l2b + i * 64, HA);
        convm_k<<<dim3(16, 8, 16), 256, 0, stream>>>(HA, X, p_rw2 + i * 9216, p_rb2 + i * 32, X);
    }

    transpose_k<<<dim3(8, 32, 16), 256, 0, stream>>>(X, Abf);
    wtr_k<<<dim3(32, 16), 256, 0, stream>>>(proj_w, 1024, 0, BtP, 2048, FLG);
    gemm_bt<<<dim3(64, 8), 256, 0, stream>>>(Abf, Abf, 2048, BtP, 2048, XP0, XP0, 1024,
                                             1 << 30, nullptr, 0, 2048, 0);

    for (int l = 0; l < 3; ++l)
        wtr_k<<<dim3(16, 48), 256, 0, stream>>>(sru_w, 3072, (size_t)l * 3145728,
                                                BtS + (size_t)l * 3145728, 1024, FLG);
    wtr_k<<<dim3(16, 8), 256, 0, stream>>>(cls_w1, 512, 0, BtC, 1024, FLG);

    float* cur = XP0;
    float* nxt = XP1;
    for (int l = 0; l < 3; ++l) {
        lnlast_k<<<8192, 256, 0, stream>>>(cur, XL, p_slng + l * 1024, p_slnb + l * 1024, 1024);
        const u16* Btl = BtS + (size_t)l * 3145728;
        for (int j = 0; j < 2; ++j) {
            int t0f = j * TC;
            int t0b = (1 - j) * TC;
            gemm_bt<<<dim3(32, 24), 256, 0, stream>>>(XL + (size_t)t0f * 16 * 1024,
                                                      XL + (size_t)t0b * 16 * 1024, 1024,
                                                      Btl, 1024, Uf, Ub, 1536, 1536,
                                                      nullptr, 0, 1024, 1);
            scan_k<<<256, 64, 0, stream>>>(Uf, Ub, cur, nxt, CST,
                                           p_sv + l * 2048, p_sb + l * 2048, t0f, t0b, j == 0);
        }
        float* tmp = cur; cur = nxt; nxt = tmp;
    }

    lnlast_k<<<8192, 256, 0, stream>>>(cur, XL, p_clng, p_clnb, 1024);
    gemm_bt<<<dim3(64, 4), 256, 0, stream>>>(XL, XL, 1024, BtC, 1024, FC1, FC1, 512,
                                             1 << 30, p_cb1, 1, 1024, 0);
    cls2_k<<<2048, 256, 0, stream>>>(FC1, p_cw2, p_cb2, d_out, FLG);
}

// Round 8
// 2028.627 us; speedup vs baseline: 1.0608x; 1.0608x over previous
//
#include <hip/hip_runtime.h>

typedef unsigned short u16;
typedef unsigned int u32;
typedef __attribute__((ext_vector_type(8))) short short8;
typedef __attribute__((ext_vector_type(4))) float floatx4;

__device__ __forceinline__ float bf2f(u16 u) {
    union { unsigned int i; float f; } v; v.i = ((unsigned int)u) << 16; return v.f;
}
__device__ __forceinline__ u16 f2bf(float f) {
    union { float f; unsigned int i; } v; v.f = f;
    unsigned int i = v.i + 0x7fffu + ((v.i >> 16) & 1u);  // RNE
    return (u16)(i >> 16);
}

// async global->LDS, 16B per lane; LDS dest must be wave-uniform base + lane*16
#define GLL(g, l) __builtin_amdgcn_global_load_lds( \
    (const __attribute__((address_space(1))) void*)(g), \
    (__attribute__((address_space(3))) void*)(l), 16, 0, 0)

// Ha halo tensor: [b][f_idx 0..65][t_idx 0..513 (pad 514)][ci 0..31] bf16
#define HA_BSTRIDE 1085568  // 66*514*32

// ---------------- dtype sniffer: flag=1 means inputs are float32 ----------------
__global__ __launch_bounds__(256) void sniff_k(const u16* __restrict__ x, int* __restrict__ flag) {
    __shared__ int red[4];
    int cnt = 0;
    for (int i = 0; i < 16; ++i) {
        u16 v = x[(threadIdx.x * 16 + i) * 2];
        int e = (v >> 7) & 0xFF;
        if (e >= 110 && e <= 135) cnt++;
    }
    #pragma unroll
    for (int off = 32; off; off >>= 1) cnt += __shfl_down(cnt, off);
    if ((threadIdx.x & 63) == 0) red[threadIdx.x >> 6] = cnt;
    __syncthreads();
    if (threadIdx.x == 0) {
        int tot = red[0] + red[1] + red[2] + red[3];
        *flag = (tot < 2048) ? 1 : 0;
    }
}

__device__ __forceinline__ float ldin(const void* p, size_t i, int isf32) {
    return isf32 ? ((const float*)p)[i] : bf2f(((const u16*)p)[i]);
}

// ---------------- canonicalize all params to f32 park (one launch) ----------------
struct CvtArgs {
    const void* src[19];
    int len[19];
    int off[19];
};
__global__ __launch_bounds__(256) void cvtall_k(CvtArgs a, float* __restrict__ dst,
                                                const int* __restrict__ flag) {
    int isf32 = *flag;
    int seg = blockIdx.y;
    int n = a.len[seg];
    const void* s = a.src[seg];
    float* d = dst + a.off[seg];
    for (int i = blockIdx.x * 256 + threadIdx.x; i < n; i += gridDim.x * 256)
        d[i] = ldin(s, i, isf32);
}

// ---------------- weight transpose: W[K][N] (dual dtype) -> Wt[N][K] bf16 ----------------
__global__ __launch_bounds__(256) void wtr_k(const void* __restrict__ W, int ldw, size_t wofs,
                                             u16* __restrict__ Wt, int ldt,
                                             const int* __restrict__ flag) {
    int isf32 = *flag;
    __shared__ u16 t[64][65];
    int k0 = blockIdx.x * 64, n0 = blockIdx.y * 64;
    int tid = threadIdx.x;
    #pragma unroll
    for (int i = 0; i < 16; ++i) {
        int kk = i * 4 + (tid >> 6), nn = tid & 63;
        t[kk][nn] = f2bf(ldin(W, wofs + (size_t)(k0 + kk) * ldw + n0 + nn, isf32));
    }
    __syncthreads();
    #pragma unroll
    for (int i = 0; i < 16; ++i) {
        int nn = i * 4 + (tid >> 6), kk = tid & 63;
        Wt[(size_t)(n0 + nn) * ldt + k0 + kk] = t[kk][nn];
    }
}

// ---------------- zero / guard fill ----------------
__global__ __launch_bounds__(256) void zero_k(float4* __restrict__ p, int n4) {
    float4 z = {0.f, 0.f, 0.f, 0.f};
    for (int i = blockIdx.x * 256 + threadIdx.x; i < n4; i += gridDim.x * 256) p[i] = z;
}
__global__ __launch_bounds__(256) void fill_k(float* __restrict__ p, int n) {
    int i = blockIdx.x * 256 + threadIdx.x;
    if (i < n) p[i] = 1.0e6f;
}

// ---------------- conv stem: 1->32, k3 s2 p1 -> X f32 NCHW; 4 co per thread ----------------
// lanes sweep t (coalesced); f, co-group, b wave-uniform (scalar weight loads).
__global__ __launch_bounds__(256) void conv1_k(const void* __restrict__ x, const float* __restrict__ w,
                                               const float* __restrict__ bias, float* __restrict__ out,
                                               const int* __restrict__ flag) {
    int isf32 = *flag;
    int idx = blockIdx.x * 256 + threadIdx.x;   // 4,194,304 threads
    int t  = idx & 511;
    int f  = (idx >> 9) & 63;
    int cg = (idx >> 15) & 7;       // co = cg*4 + i
    int b  = idx >> 18;
    size_t xb = (size_t)b * 128 * 1024;

    float wr[4][9];
    #pragma unroll
    for (int i = 0; i < 4; ++i)
        #pragma unroll
        for (int k = 0; k < 9; ++k) wr[i][k] = w[(cg * 4 + i) * 9 + k];

    float acc[4];
    #pragma unroll
    for (int i = 0; i < 4; ++i) acc[i] = bias[cg * 4 + i];

    #pragma unroll
    for (int df = 0; df < 3; ++df) {
        int fi = 2 * f + df - 1;
        if (fi < 0 || fi >= 128) continue;       // wave-uniform branch
        size_t rowb = xb + (size_t)fi * 1024;
        float xv[3];
        #pragma unroll
        for (int dt = 0; dt < 3; ++dt) {
            int ti = 2 * t + dt - 1;
            float v = 0.f;
            if (ti >= 0 && ti < 1024) v = ldin(x, rowb + ti, isf32);
            xv[dt] = v;
        }
        #pragma unroll
        for (int i = 0; i < 4; ++i)
            #pragma unroll
            for (int dt = 0; dt < 3; ++dt)
                acc[i] = fmaf(wr[i][df * 3 + dt], xv[dt], acc[i]);
    }
    size_t obase = (((size_t)b * 32 + cg * 4) * 64 + f) * 512 + t;
    #pragma unroll
    for (int i = 0; i < 4; ++i) out[obase + (size_t)i * 64 * 512] = acc[i];
}

// ---------------- LN-over-f stats (dual-dtype input, NCHW) ----------------
__global__ __launch_bounds__(256) void stats_k(const void* __restrict__ X, int isbf,
                                               float* __restrict__ sm, float* __restrict__ sr) {
    int idx = blockIdx.x * 256 + threadIdx.x;  // 16*32*512
    int t  = idx & 511;
    int bc = idx >> 9;
    size_t base = (size_t)bc * 64 * 512 + t;
    float s = 0.f, s2 = 0.f;
    #pragma unroll 8
    for (int f = 0; f < 64; ++f) {
        float v = isbf ? bf2f(((const u16*)X)[base + f * 512]) : ((const float*)X)[base + f * 512];
        s += v; s2 += v * v;
    }
    float m  = s * (1.f / 64.f);
    float var = fmaxf(s2 * (1.f / 64.f) - m * m, 0.f);
    sm[idx] = m;
    sr[idx] = rsqrtf(var + 1e-5f);
}

// ---------------- apply LN+ReLU: NCHW (f32|bf16) -> Ha NHWC halo bf16 ----------------
__global__ __launch_bounds__(256) void apply_k(const void* __restrict__ in, int isbf,
                                               const float* __restrict__ sm, const float* __restrict__ sr,
                                               const float* __restrict__ g, const float* __restrict__ be,
                                               u16* __restrict__ Ha) {
    int f = blockIdx.x;
    int b = blockIdx.y;
    float gg = g[f], bb_ = be[f];
    for (int it = 0; it < 2; ++it) {
        int t = it * 256 + threadIdx.x;
        u32 pk[16];
        #pragma unroll
        for (int cp = 0; cp < 16; ++cp) {
            u32 w = 0;
            #pragma unroll
            for (int half = 0; half < 2; ++half) {
                int ci = cp * 2 + half;
                size_t xi = (((size_t)b * 32 + ci) * 64 + f) * 512 + t;
                float xv = isbf ? bf2f(((const u16*)in)[xi]) : ((const float*)in)[xi];
                int si = (b * 32 + ci) * 512 + t;
                float hv = fmaxf((xv - sm[si]) * sr[si] * gg + bb_, 0.f);
                w |= ((u32)f2bf(hv)) << (half * 16);
            }
            pk[cp] = w;
        }
        u32* orow = (u32*)(Ha + (size_t)b * HA_BSTRIDE + ((size_t)(f + 1) * 514 + (t + 1)) * 32);
        #pragma unroll
        for (int q = 0; q < 16; ++q) orow[q] = pk[q];
    }
}

// ---------------- conv32 k3 s1 p1 via MFMA, GLL staging from Ha ----------------
__global__ __launch_bounds__(256) void convm_k(const u16* __restrict__ Ha, void* __restrict__ out,
                                               const float* __restrict__ w, const float* __restrict__ bias,
                                               const float* __restrict__ res) {
    __shared__ u16 act[6 * 66 * 32];  // 25344 B
    int f0 = blockIdx.x * 4;
    int t0 = blockIdx.y * 64;
    int b  = blockIdx.z;
    const u16* Hb = Ha + (size_t)b * HA_BSTRIDE;

    int lane = threadIdx.x & 63;
    int wv   = threadIdx.x >> 6;
    int quad = lane >> 4;
    int r    = lane & 15;

    for (int u = threadIdx.x; u < 1584; u += 256) {
        int fp  = u / 264;
        int rem = u - fp * 264;
        int tp  = rem >> 2;
        int q   = rem & 3;
        const u16* gp = Hb + ((size_t)(f0 + fp) * 514 + (t0 + tp)) * 32 + q * 8;
        GLL(gp, act + u * 8);
    }

    short8 bfrag[3][3][2];
    #pragma unroll
    for (int df = 0; df < 3; ++df)
        #pragma unroll
        for (int dt = 0; dt < 3; ++dt)
            #pragma unroll
            for (int ct = 0; ct < 2; ++ct) {
                short8 v;
                #pragma unroll
                for (int j = 0; j < 8; ++j) {
                    int co = ct * 16 + r, ci = quad * 8 + j;
                    v[j] = (short)f2bf(w[(co * 32 + ci) * 9 + df * 3 + dt]);
                }
                bfrag[df][dt][ct] = v;
            }
    __syncthreads();

    floatx4 acc[4][2];
    #pragma unroll
    for (int i = 0; i < 4; ++i)
        #pragma unroll
        for (int j = 0; j < 2; ++j)
            #pragma unroll
            for (int k = 0; k < 4; ++k) acc[i][j][k] = 0.f;

    int tw = wv * 16;
    #pragma unroll
    for (int fh = 0; fh < 6; ++fh) {
        short8 af[3];
        #pragma unroll
        for (int dt = 0; dt < 3; ++dt)
            af[dt] = *(const short8*)&act[((fh * 66) + tw + r + dt) * 32 + quad * 8];
        #pragma unroll
        for (int df = 0; df < 3; ++df) {
            int rel = fh - df;
            if (rel < 0 || rel >= 4) continue;
            #pragma unroll
            for (int dt = 0; dt < 3; ++dt)
                #pragma unroll
                for (int ct = 0; ct < 2; ++ct)
                    acc[rel][ct] = __builtin_amdgcn_mfma_f32_16x16x32_bf16(
                        af[dt], bfrag[df][dt][ct], acc[rel][ct], 0, 0, 0);
        }
    }

    int tt = t0 + tw + quad * 4;
    #pragma unroll
    for (int rel = 0; rel < 4; ++rel)
        #pragma unroll
        for (int ct = 0; ct < 2; ++ct) {
            int f  = f0 + rel;
            int co = ct * 16 + r;
            size_t base = (((size_t)b * 32 + co) * 64 + f) * 512 + tt;
            float bs = bias[co];
            if (res) {
                float4 rv = *(const float4*)(res + base);
                float4 o;
                o.x = acc[rel][ct][0] + bs + rv.x;
                o.y = acc[rel][ct][1] + bs + rv.y;
                o.z = acc[rel][ct][2] + bs + rv.z;
                o.w = acc[rel][ct][3] + bs + rv.w;
                *(float4*)((float*)out + base) = o;
            } else {
                ushort4 o;
                o.x = f2bf(acc[rel][ct][0] + bs);
                o.y = f2bf(acc[rel][ct][1] + bs);
                o.z = f2bf(acc[rel][ct][2] + bs);
                o.w = f2bf(acc[rel][ct][3] + bs);
                *(ushort4*)((u16*)out + base) = o;
            }
        }
}

// ---------------- transpose X (b,c,f,t) f32 -> A[(t*16+b)][(c*64+f)] bf16 ----------------
__global__ __launch_bounds__(256) void transpose_k(const float* __restrict__ X, u16* __restrict__ A) {
    __shared__ float tile[64][65];
    int t0 = blockIdx.x * 64;
    int c  = blockIdx.y;
    int b  = blockIdx.z;
    const float* p = X + (((size_t)b * 32 + c) * 64) * 512 + t0;
    #pragma unroll
    for (int i = 0; i < 16; ++i) {
        int f = i * 4 + (threadIdx.x >> 6);
        int t = threadIdx.x & 63;
        tile[f][t] = p[(size_t)f * 512 + t];
    }
    __syncthreads();
    #pragma unroll
    for (int i = 0; i < 16; ++i) {
        int t = i * 4 + (threadIdx.x >> 6);
        int f = threadIdx.x & 63;
        A[((size_t)(t0 + t) * 16 + b) * 2048 + c * 64 + f] = f2bf(tile[f][t]);
    }
}

// ---------------- row layernorm, f32 in -> bf16 out ----------------
__global__ __launch_bounds__(256) void lnlast_k(const float* __restrict__ X, u16* __restrict__ Y,
                                                const float* __restrict__ g, const float* __restrict__ bt,
                                                int width) {
    int row = blockIdx.x;
    const float* p = X + (size_t)row * width;
    float s = 0.f, s2 = 0.f;
    for (int i = threadIdx.x; i < width; i += 256) { float v = p[i]; s += v; s2 += v * v; }
    #pragma unroll
    for (int off = 32; off; off >>= 1) { s += __shfl_down(s, off); s2 += __shfl_down(s2, off); }
    __shared__ float red[4][2];
    int wv = threadIdx.x >> 6;
    if ((threadIdx.x & 63) == 0) { red[wv][0] = s; red[wv][1] = s2; }
    __syncthreads();
    if (threadIdx.x == 0) {
        float a = 0.f, b2 = 0.f;
        for (int i = 0; i < 4; ++i) { a += red[i][0]; b2 += red[i][1]; }
        float m = a / width;
        float var = fmaxf(b2 / width - m * m, 0.f);
        red[0][0] = m; red[0][1] = rsqrtf(var + 1e-5f);
    }
    __syncthreads();
    float m = red[0][0], rs = red[0][1];
    u16* q = Y + (size_t)row * width;
    for (int i = threadIdx.x; i < width; i += 256)
        q[i] = f2bf((p[i] - m) * rs * g[i] + bt[i]);
}

// ---------------- m97-style MFMA GEMM: C = A @ Bt^T, 128x128, BK=32, GLL staging ----------
__global__ __launch_bounds__(256) void gemm_bt(const u16* __restrict__ A, const u16* __restrict__ A2,
                                               int lda, const u16* __restrict__ Bt, int ldb,
                                               void* __restrict__ C, void* __restrict__ C2,
                                               int ldc, int nsplit,
                                               const float* __restrict__ bias, int relu, int K,
                                               int obf) {
    __shared__ u16 As[128 * 32];
    __shared__ u16 Bs[128 * 32];
    int tid  = threadIdx.x;
    int bm   = blockIdx.x * 128;
    int bn   = blockIdx.y * 128;
    const u16* Ab = A;
    void* Cb = C;
    int cn = bn;
    if (bn >= nsplit) { Ab = A2; Cb = C2; cn = bn - nsplit; }

    int lane = tid & 63;
    int wv   = tid >> 6;
    int quad = lane >> 4;
    int r    = lane & 15;
    int wm   = (wv >> 1) * 64;
    int wn   = (wv & 1) * 64;

    floatx4 acc[4][4];
    #pragma unroll
    for (int i = 0; i < 4; ++i)
        #pragma unroll
        for (int j = 0; j < 4; ++j)
            #pragma unroll
            for (int k = 0; k < 4; ++k) acc[i][j][k] = 0.f;

    int row0 = tid >> 2;
    int ks0  = (tid & 3) * 8;
    const u16* Abase  = Ab + (size_t)(bm + row0) * lda + ks0;
    const u16* Abase2 = Ab + (size_t)(bm + 64 + row0) * lda + ks0;
    const u16* Bbase  = Bt + (size_t)(bn + row0) * ldb + ks0;
    const u16* Bbase2 = Bt + (size_t)(bn + 64 + row0) * ldb + ks0;
    u16* AsD  = As + tid * 8;
    u16* AsD2 = As + 2048 + tid * 8;
    u16* BsD  = Bs + tid * 8;
    u16* BsD2 = Bs + 2048 + tid * 8;

    for (int k0 = 0; k0 < K; k0 += 32) {
        GLL(Abase + k0, AsD);
        GLL(Abase2 + k0, AsD2);
        GLL(Bbase + k0, BsD);
        GLL(Bbase2 + k0, BsD2);
        __syncthreads();
        short8 af[4], bf[4];
        #pragma unroll
        for (int mi = 0; mi < 4; ++mi) af[mi] = *(const short8*)&As[(wm + mi * 16 + r) * 32 + quad * 8];
        #pragma unroll
        for (int ni = 0; ni < 4; ++ni) bf[ni] = *(const short8*)&Bs[(wn + ni * 16 + r) * 32 + quad * 8];
        #pragma unroll
        for (int mi = 0; mi < 4; ++mi)
            #pragma unroll
            for (int ni = 0; ni < 4; ++ni)
                acc[mi][ni] = __builtin_amdgcn_mfma_f32_16x16x32_bf16(af[mi], bf[ni], acc[mi][ni], 0, 0, 0);
        __syncthreads();
    }

    #pragma unroll
    for (int mi = 0; mi < 4; ++mi)
        #pragma unroll
        for (int ni = 0; ni < 4; ++ni) {
            int col = cn + wn + ni * 16 + r;
            float bs = bias ? bias[col] : 0.f;
            #pragma unroll
            for (int reg = 0; reg < 4; ++reg) {
                int row = bm + wm + mi * 16 + quad * 4 + reg;
                float v = acc[mi][ni][reg] + bs;
                if (relu) v = fmaxf(v, 0.f);
                if (obf) ((u16*)Cb)[(size_t)row * ldc + col] = f2bf(v);
                else     ((float*)Cb)[(size_t)row * ldc + col] = v;
            }
        }
}

// ---------------- SRU recurrence: ring-4 prefetch, 2 waves/CU over 128 CUs ----------------
#define TC 256
#define PD 4
__global__ __launch_bounds__(128) void scan_k(const u16* __restrict__ Uf, const u16* __restrict__ Ub,
                                              const float* __restrict__ Xp, float* __restrict__ Xn,
                                              float* __restrict__ cstate, const float* __restrict__ vv,
                                              const float* __restrict__ bb, int t0f, int t0b, int init) {
    int gid = blockIdx.x * 128 + threadIdx.x;  // 16384
    int d  = gid >> 13;
    int b  = (gid >> 9) & 15;
    int h  = gid & 511;
    float v0 = vv[(d * 2 + 0) * 512 + h];
    float v1 = vv[(d * 2 + 1) * 512 + h];
    float b0 = bb[(d * 2 + 0) * 512 + h];
    float b1 = bb[(d * 2 + 1) * 512 + h];
    const u16* u = (d ? Ub : Uf) + (size_t)b * 1536 + h;
    int t0 = d ? t0b : t0f;
    const float* xb = Xp + (size_t)b * 1024 + d * 512 + h;
    float*       ob = Xn + (size_t)b * 1024 + d * 512 + h;
    float c = init ? 0.f : cstate[gid];

    float pu0[PD], pfp[PD], prp[PD], pxr[PD];
    #pragma unroll
    for (int s = 0; s < PD; ++s) {
        int sl = d ? (TC - 1 - s) : s;
        size_t ro = (size_t)sl * 16 * 1536;
        pu0[s] = bf2f(u[ro]);
        pfp[s] = bf2f(u[ro + 512]);
        prp[s] = bf2f(u[ro + 1024]);
        pxr[s] = xb[(size_t)(t0 + sl) * 16 * 1024];
    }
    #pragma unroll 4
    for (int s = 0; s < TC; ++s) {
        int slot = s & (PD - 1);
        float u0 = pu0[slot], fp_ = pfp[slot], rp_ = prp[slot], xr = pxr[slot];
        int sp = s + PD;
        if (sp < TC) {
            int sl2 = d ? (TC - 1 - sp) : sp;
            size_t ro2 = (size_t)sl2 * 16 * 1536;
            pu0[slot] = bf2f(u[ro2]);
            pfp[slot] = bf2f(u[ro2 + 512]);
            prp[slot] = bf2f(u[ro2 + 1024]);
            pxr[slot] = xb[(size_t)(t0 + sl2) * 16 * 1024];
        }
        float f = 1.f / (1.f + __expf(-(fp_ + b0 + v0 * c)));
        float r = 1.f / (1.f + __expf(-(rp_ + b1 + v1 * c)));
        c = f * c + (1.f - f) * u0;
        float th = 1.f - 2.f / (__expf(2.f * c) + 1.f);
        int sl = d ? (TC - 1 - s) : s;
        ob[(size_t)(t0 + sl) * 16 * 1024] = r * th + (1.f - r) * xr;
    }
    cstate[gid] = c;
}

// ---------------- classifier head ----------------
__global__ __launch_bounds__(256) void cls2_k(const float* __restrict__ FC1, const float* __restrict__ W2,
                                              const float* __restrict__ b2, void* __restrict__ out,
                                              const int* __restrict__ flag) {
    int isf32 = *flag;
    int row = blockIdx.x * 4 + (threadIdx.x >> 6);
    int v   = threadIdx.x & 63;
    if (v >= 29) return;
    const float* p = FC1 + (size_t)row * 512;
    float acc = 0.f;
    for (int k = 0; k < 512; ++k) acc = fmaf(p[k], W2[k * 29 + v], acc);
    acc += b2[v];
    int t = row >> 4, b = row & 15;
    size_t oi = ((size_t)b * 512 + t) * 29 + v;
    if (isf32) ((float*)out)[oi] = acc;
    else       ((u16*)out)[oi]   = f2bf(acc);
}

// ---------------- launch ----------------
extern "C" void kernel_launch(void* const* d_in, const int* in_sizes, int n_in,
                              void* d_out, int out_size, void* d_ws, size_t ws_size,
                              hipStream_t stream) {
    const void* x      = d_in[0];
    const void* proj_w = d_in[11];
    const void* sru_w  = d_in[12];
    const void* cls_w1 = d_in[19];

    float* ws = (float*)d_ws;
    const size_t O_X    = 0;
    const size_t O_C    = 16777216;
    const size_t O_HA   = 25165824;
    const size_t O_SM   = 33850368;
    const size_t O_SR   = 34112512;
    const size_t O_CST  = 34374656;
    const size_t O_PARK = 34391040;
    const size_t O_FLAG = 34483488;
    const size_t TOTAL  = 34483504;   // 131.55 MiB
    if (ws_size < TOTAL * sizeof(float)) {
        fill_k<<<(out_size + 255) / 256, 256, 0, stream>>>((float*)d_out, out_size);
        return;
    }

    float* X   = ws + O_X;
    u16*   C   = (u16*)(ws + O_C);
    u16*   HA  = (u16*)(ws + O_HA);
    float* SM  = ws + O_SM;
    float* SR  = ws + O_SR;
    float* CST = ws + O_CST;
    float* PK  = ws + O_PARK;
    int*   FLG = (int*)(ws + O_FLAG);

    u16*   Abf = (u16*)(ws + O_C);
    u16*   BtP = (u16*)(ws + 0);
    float* XP0 = ws + 25165824;
    u16*   XL  = (u16*)(ws + 0);
    float* XP1 = ws + 4194304;
    u16*   Uf  = (u16*)(ws + 12582912);
    u16*   Ub  = (u16*)(ws + 15728640);
    u16*   BtS = (u16*)(ws + 18874368);
    u16*   BtC = (u16*)(ws + O_SM);
    float* FC1 = ws + 12582912;

    float* p_cnn_w = PK + 0;      float* p_cnn_b = PK + 288;
    float* p_rw1   = PK + 320;    float* p_rb1   = PK + 27968;
    float* p_rw2   = PK + 28064;  float* p_rb2   = PK + 55712;
    float* p_l1g   = PK + 55808;  float* p_l1b   = PK + 56000;
    float* p_l2g   = PK + 56192;  float* p_l2b   = PK + 56384;
    float* p_sv    = PK + 56576;  float* p_sb    = PK + 62720;
    float* p_slng  = PK + 68864;  float* p_slnb  = PK + 71936;
    float* p_clng  = PK + 75008;  float* p_clnb  = PK + 76032;
    float* p_cb1   = PK + 77056;  float* p_cw2   = PK + 77568;
    float* p_cb2   = PK + 92416;

    sniff_k<<<1, 256, 0, stream>>>((const u16*)x, FLG);

    CvtArgs ca;
    const int srcidx[19] = {1,2,3,4,5,6,7,8,9,10,13,14,15,16,17,18,20,21,22};
    const int lens[19]   = {288,32,27648,96,27648,96,192,192,192,192,6144,6144,3072,3072,1024,1024,512,14848,29};
    const int offs[19]   = {0,288,320,27968,28064,55712,55808,56000,56192,56384,56576,62720,68864,71936,75008,76032,77056,77568,92416};
    for (int i = 0; i < 19; ++i) { ca.src[i] = d_in[srcidx[i]]; ca.len[i] = lens[i]; ca.off[i] = offs[i]; }
    cvtall_k<<<dim3(108, 19), 256, 0, stream>>>(ca, PK, FLG);

    zero_k<<<2048, 256, 0, stream>>>((float4*)HA, 2171136);
    conv1_k<<<16384, 256, 0, stream>>>(x, p_cnn_w, p_cnn_b, X, FLG);

    for (int i = 0; i < 3; ++i) {
        stats_k<<<1024, 256, 0, stream>>>(X, 0, SM, SR);
        apply_k<<<dim3(64, 16), 256, 0, stream>>>(X, 0, SM, SR, p_l1g + i * 64, p_l1b + i * 64, HA);
        convm_k<<<dim3(16, 8, 16), 256, 0, stream>>>(HA, C, p_rw1 + i * 9216, p_rb1 + i * 32, nullptr);
        stats_k<<<1024, 256, 0, stream>>>(C, 1, SM, SR);
        apply_k<<<dim3(64, 16), 256, 0, stream>>>(C, 1, SM, SR, p_l2g + i * 64, p_l2b + i * 64, HA);
        convm_k<<<dim3(16, 8, 16), 256, 0, stream>>>(HA, X, p_rw2 + i * 9216, p_rb2 + i * 32, X);
    }

    transpose_k<<<dim3(8, 32, 16), 256, 0, stream>>>(X, Abf);
    wtr_k<<<dim3(32, 16), 256, 0, stream>>>(proj_w, 1024, 0, BtP, 2048, FLG);
    gemm_bt<<<dim3(64, 8), 256, 0, stream>>>(Abf, Abf, 2048, BtP, 2048, XP0, XP0, 1024,
                                             1 << 30, nullptr, 0, 2048, 0);

    for (int l = 0; l < 3; ++l)
        wtr_k<<<dim3(16, 48), 256, 0, stream>>>(sru_w, 3072, (size_t)l * 3145728,
                                                BtS + (size_t)l * 3145728, 1024, FLG);
    wtr_k<<<dim3(16, 8), 256, 0, stream>>>(cls_w1, 512, 0, BtC, 1024, FLG);

    float* cur = XP0;
    float* nxt = XP1;
    for (int l = 0; l < 3; ++l) {
        lnlast_k<<<8192, 256, 0, stream>>>(cur, XL, p_slng + l * 1024, p_slnb + l * 1024, 1024);
        const u16* Btl = BtS + (size_t)l * 3145728;
        for (int j = 0; j < 2; ++j) {
            int t0f = j * TC;
            int t0b = (1 - j) * TC;
            gemm_bt<<<dim3(32, 24), 256, 0, stream>>>(XL + (size_t)t0f * 16 * 1024,
                                                      XL + (size_t)t0b * 16 * 1024, 1024,
                                                      Btl, 1024, Uf, Ub, 1536, 1536,
                                                      nullptr, 0, 1024, 1);
            scan_k<<<128, 128, 0, stream>>>(Uf, Ub, cur, nxt, CST,
                                            p_sv + l * 2048, p_sb + l * 2048, t0f, t0b, j == 0);
        }
        float* tmp = cur; cur = nxt; nxt = tmp;
    }

    lnlast_k<<<8192, 256, 0, stream>>>(cur, XL, p_clng, p_clnb, 1024);
    gemm_bt<<<dim3(64, 4), 256, 0, stream>>>(XL, XL, 1024, BtC, 1024, FC1, FC1, 512,
                                             1 << 30, p_cb1, 1, 1024, 0);
    cls2_k<<<2048, 256, 0, stream>>>(FC1, p_cw2, p_cb2, d_out, FLG);
}

// Round 9
// 1588.166 us; speedup vs baseline: 1.3549x; 1.2773x over previous
//
#include <hip/hip_runtime.h>

typedef unsigned short u16;
typedef unsigned int u32;
typedef __attribute__((ext_vector_type(8))) short short8;
typedef __attribute__((ext_vector_type(4))) float floatx4;

__device__ __forceinline__ float bf2f(u16 u) {
    union { unsigned int i; float f; } v; v.i = ((unsigned int)u) << 16; return v.f;
}
__device__ __forceinline__ u16 f2bf(float f) {
    union { float f; unsigned int i; } v; v.f = f;
    unsigned int i = v.i + 0x7fffu + ((v.i >> 16) & 1u);  // RNE
    return (u16)(i >> 16);
}

// async global->LDS, 16B per lane; LDS dest must be wave-uniform base + lane*16
#define GLL(g, l) __builtin_amdgcn_global_load_lds( \
    (const __attribute__((address_space(1))) void*)(g), \
    (__attribute__((address_space(3))) void*)(l), 16, 0, 0)

// Ha halo tensor: [b][f_idx 0..65][t_idx 0..513 (pad 514)][ci 0..31] bf16
#define HA_BSTRIDE 1085568  // 66*514*32

// ---------------- dtype sniffer: flag=1 means inputs are float32 ----------------
__global__ __launch_bounds__(256) void sniff_k(const u16* __restrict__ x, int* __restrict__ flag) {
    __shared__ int red[4];
    int cnt = 0;
    for (int i = 0; i < 16; ++i) {
        u16 v = x[(threadIdx.x * 16 + i) * 2];
        int e = (v >> 7) & 0xFF;
        if (e >= 110 && e <= 135) cnt++;
    }
    #pragma unroll
    for (int off = 32; off; off >>= 1) cnt += __shfl_down(cnt, off);
    if ((threadIdx.x & 63) == 0) red[threadIdx.x >> 6] = cnt;
    __syncthreads();
    if (threadIdx.x == 0) {
        int tot = red[0] + red[1] + red[2] + red[3];
        *flag = (tot < 2048) ? 1 : 0;
    }
}

__device__ __forceinline__ float ldin(const void* p, size_t i, int isf32) {
    return isf32 ? ((const float*)p)[i] : bf2f(((const u16*)p)[i]);
}

// ---------------- canonicalize all params to f32 park (one launch) ----------------
struct CvtArgs {
    const void* src[19];
    int len[19];
    int off[19];
};
__global__ __launch_bounds__(256) void cvtall_k(CvtArgs a, float* __restrict__ dst,
                                                const int* __restrict__ flag) {
    int isf32 = *flag;
    int seg = blockIdx.y;
    int n = a.len[seg];
    const void* s = a.src[seg];
    float* d = dst + a.off[seg];
    for (int i = blockIdx.x * 256 + threadIdx.x; i < n; i += gridDim.x * 256)
        d[i] = ldin(s, i, isf32);
}

// ---------------- weight transpose: W[K][N] (dual dtype) -> Wt[N][K] bf16 ----------------
__global__ __launch_bounds__(256) void wtr_k(const void* __restrict__ W, int ldw, size_t wofs,
                                             u16* __restrict__ Wt, int ldt,
                                             const int* __restrict__ flag) {
    int isf32 = *flag;
    __shared__ u16 t[64][65];
    int k0 = blockIdx.x * 64, n0 = blockIdx.y * 64;
    int tid = threadIdx.x;
    #pragma unroll
    for (int i = 0; i < 16; ++i) {
        int kk = i * 4 + (tid >> 6), nn = tid & 63;
        t[kk][nn] = f2bf(ldin(W, wofs + (size_t)(k0 + kk) * ldw + n0 + nn, isf32));
    }
    __syncthreads();
    #pragma unroll
    for (int i = 0; i < 16; ++i) {
        int nn = i * 4 + (tid >> 6), kk = tid & 63;
        Wt[(size_t)(n0 + nn) * ldt + k0 + kk] = t[kk][nn];
    }
}

// ---------------- zero / guard fill ----------------
__global__ __launch_bounds__(256) void zero_k(float4* __restrict__ p, int n4) {
    float4 z = {0.f, 0.f, 0.f, 0.f};
    for (int i = blockIdx.x * 256 + threadIdx.x; i < n4; i += gridDim.x * 256) p[i] = z;
}
__global__ __launch_bounds__(256) void fill_k(float* __restrict__ p, int n) {
    int i = blockIdx.x * 256 + threadIdx.x;
    if (i < n) p[i] = 1.0e6f;
}

// ---------------- conv stem: 1->32, k3 s2 p1 -> X f32 NCHW; 4 co per thread ----------------
__global__ __launch_bounds__(256) void conv1_k(const void* __restrict__ x, const float* __restrict__ w,
                                               const float* __restrict__ bias, float* __restrict__ out,
                                               const int* __restrict__ flag) {
    int isf32 = *flag;
    int idx = blockIdx.x * 256 + threadIdx.x;   // 4,194,304 threads
    int t  = idx & 511;
    int f  = (idx >> 9) & 63;
    int cg = (idx >> 15) & 7;       // co = cg*4 + i
    int b  = idx >> 18;
    size_t xb = (size_t)b * 128 * 1024;

    float wr[4][9];
    #pragma unroll
    for (int i = 0; i < 4; ++i)
        #pragma unroll
        for (int k = 0; k < 9; ++k) wr[i][k] = w[(cg * 4 + i) * 9 + k];

    float acc[4];
    #pragma unroll
    for (int i = 0; i < 4; ++i) acc[i] = bias[cg * 4 + i];

    #pragma unroll
    for (int df = 0; df < 3; ++df) {
        int fi = 2 * f + df - 1;
        if (fi < 0 || fi >= 128) continue;       // wave-uniform branch
        size_t rowb = xb + (size_t)fi * 1024;
        float xv[3];
        #pragma unroll
        for (int dt = 0; dt < 3; ++dt) {
            int ti = 2 * t + dt - 1;
            float v = 0.f;
            if (ti >= 0 && ti < 1024) v = ldin(x, rowb + ti, isf32);
            xv[dt] = v;
        }
        #pragma unroll
        for (int i = 0; i < 4; ++i)
            #pragma unroll
            for (int dt = 0; dt < 3; ++dt)
                acc[i] = fmaf(wr[i][df * 3 + dt], xv[dt], acc[i]);
    }
    size_t obase = (((size_t)b * 32 + cg * 4) * 64 + f) * 512 + t;
    #pragma unroll
    for (int i = 0; i < 4; ++i) out[obase + (size_t)i * 64 * 512] = acc[i];
}

// ---------------- LN-over-f stats (dual-dtype input, NCHW) ----------------
__global__ __launch_bounds__(256) void stats_k(const void* __restrict__ X, int isbf,
                                               float* __restrict__ sm, float* __restrict__ sr) {
    int idx = blockIdx.x * 256 + threadIdx.x;  // 16*32*512
    int t  = idx & 511;
    int bc = idx >> 9;
    size_t base = (size_t)bc * 64 * 512 + t;
    float s = 0.f, s2 = 0.f;
    #pragma unroll 8
    for (int f = 0; f < 64; ++f) {
        float v = isbf ? bf2f(((const u16*)X)[base + f * 512]) : ((const float*)X)[base + f * 512];
        s += v; s2 += v * v;
    }
    float m  = s * (1.f / 64.f);
    float var = fmaxf(s2 * (1.f / 64.f) - m * m, 0.f);
    sm[idx] = m;
    sr[idx] = rsqrtf(var + 1e-5f);
}

// ---------------- apply LN+ReLU: NCHW (f32|bf16) -> Ha NHWC halo bf16 ----------------
__global__ __launch_bounds__(256) void apply_k(const void* __restrict__ in, int isbf,
                                               const float* __restrict__ sm, const float* __restrict__ sr,
                                               const float* __restrict__ g, const float* __restrict__ be,
                                               u16* __restrict__ Ha) {
    int f = blockIdx.x;
    int b = blockIdx.y;
    float gg = g[f], bb_ = be[f];
    for (int it = 0; it < 2; ++it) {
        int t = it * 256 + threadIdx.x;
        u32 pk[16];
        #pragma unroll
        for (int cp = 0; cp < 16; ++cp) {
            u32 w = 0;
            #pragma unroll
            for (int half = 0; half < 2; ++half) {
                int ci = cp * 2 + half;
                size_t xi = (((size_t)b * 32 + ci) * 64 + f) * 512 + t;
                float xv = isbf ? bf2f(((const u16*)in)[xi]) : ((const float*)in)[xi];
                int si = (b * 32 + ci) * 512 + t;
                float hv = fmaxf((xv - sm[si]) * sr[si] * gg + bb_, 0.f);
                w |= ((u32)f2bf(hv)) << (half * 16);
            }
            pk[cp] = w;
        }
        u32* orow = (u32*)(Ha + (size_t)b * HA_BSTRIDE + ((size_t)(f + 1) * 514 + (t + 1)) * 32);
        #pragma unroll
        for (int q = 0; q < 16; ++q) orow[q] = pk[q];
    }
}

// ---------------- conv32 k3 s1 p1 via MFMA, GLL staging from Ha ----------------
__global__ __launch_bounds__(256) void convm_k(const u16* __restrict__ Ha, void* __restrict__ out,
                                               const float* __restrict__ w, const float* __restrict__ bias,
                                               const float* __restrict__ res) {
    __shared__ u16 act[6 * 66 * 32];  // 25344 B
    int f0 = blockIdx.x * 4;
    int t0 = blockIdx.y * 64;
    int b  = blockIdx.z;
    const u16* Hb = Ha + (size_t)b * HA_BSTRIDE;

    int lane = threadIdx.x & 63;
    int wv   = threadIdx.x >> 6;
    int quad = lane >> 4;
    int r    = lane & 15;

    for (int u = threadIdx.x; u < 1584; u += 256) {
        int fp  = u / 264;
        int rem = u - fp * 264;
        int tp  = rem >> 2;
        int q   = rem & 3;
        const u16* gp = Hb + ((size_t)(f0 + fp) * 514 + (t0 + tp)) * 32 + q * 8;
        GLL(gp, act + u * 8);
    }

    short8 bfrag[3][3][2];
    #pragma unroll
    for (int df = 0; df < 3; ++df)
        #pragma unroll
        for (int dt = 0; dt < 3; ++dt)
            #pragma unroll
            for (int ct = 0; ct < 2; ++ct) {
                short8 v;
                #pragma unroll
                for (int j = 0; j < 8; ++j) {
                    int co = ct * 16 + r, ci = quad * 8 + j;
                    v[j] = (short)f2bf(w[(co * 32 + ci) * 9 + df * 3 + dt]);
                }
                bfrag[df][dt][ct] = v;
            }
    __syncthreads();

    floatx4 acc[4][2];
    #pragma unroll
    for (int i = 0; i < 4; ++i)
        #pragma unroll
        for (int j = 0; j < 2; ++j)
            #pragma unroll
            for (int k = 0; k < 4; ++k) acc[i][j][k] = 0.f;

    int tw = wv * 16;
    #pragma unroll
    for (int fh = 0; fh < 6; ++fh) {
        short8 af[3];
        #pragma unroll
        for (int dt = 0; dt < 3; ++dt)
            af[dt] = *(const short8*)&act[((fh * 66) + tw + r + dt) * 32 + quad * 8];
        #pragma unroll
        for (int df = 0; df < 3; ++df) {
            int rel = fh - df;
            if (rel < 0 || rel >= 4) continue;
            #pragma unroll
            for (int dt = 0; dt < 3; ++dt)
                #pragma unroll
                for (int ct = 0; ct < 2; ++ct)
                    acc[rel][ct] = __builtin_amdgcn_mfma_f32_16x16x32_bf16(
                        af[dt], bfrag[df][dt][ct], acc[rel][ct], 0, 0, 0);
        }
    }

    int tt = t0 + tw + quad * 4;
    #pragma unroll
    for (int rel = 0; rel < 4; ++rel)
        #pragma unroll
        for (int ct = 0; ct < 2; ++ct) {
            int f  = f0 + rel;
            int co = ct * 16 + r;
            size_t base = (((size_t)b * 32 + co) * 64 + f) * 512 + tt;
            float bs = bias[co];
            if (res) {
                float4 rv = *(const float4*)(res + base);
                float4 o;
                o.x = acc[rel][ct][0] + bs + rv.x;
                o.y = acc[rel][ct][1] + bs + rv.y;
                o.z = acc[rel][ct][2] + bs + rv.z;
                o.w = acc[rel][ct][3] + bs + rv.w;
                *(float4*)((float*)out + base) = o;
            } else {
                ushort4 o;
                o.x = f2bf(acc[rel][ct][0] + bs);
                o.y = f2bf(acc[rel][ct][1] + bs);
                o.z = f2bf(acc[rel][ct][2] + bs);
                o.w = f2bf(acc[rel][ct][3] + bs);
                *(ushort4*)((u16*)out + base) = o;
            }
        }
}

// ---------------- transpose X (b,c,f,t) f32 -> A[(t*16+b)][(c*64+f)] bf16 ----------------
__global__ __launch_bounds__(256) void transpose_k(const float* __restrict__ X, u16* __restrict__ A) {
    __shared__ float tile[64][65];
    int t0 = blockIdx.x * 64;
    int c  = blockIdx.y;
    int b  = blockIdx.z;
    const float* p = X + (((size_t)b * 32 + c) * 64) * 512 + t0;
    #pragma unroll
    for (int i = 0; i < 16; ++i) {
        int f = i * 4 + (threadIdx.x >> 6);
        int t = threadIdx.x & 63;
        tile[f][t] = p[(size_t)f * 512 + t];
    }
    __syncthreads();
    #pragma unroll
    for (int i = 0; i < 16; ++i) {
        int t = i * 4 + (threadIdx.x >> 6);
        int f = threadIdx.x & 63;
        A[((size_t)(t0 + t) * 16 + b) * 2048 + c * 64 + f] = f2bf(tile[f][t]);
    }
}

// ---------------- row layernorm, f32 in -> bf16 out ----------------
__global__ __launch_bounds__(256) void lnlast_k(const float* __restrict__ X, u16* __restrict__ Y,
                                                const float* __restrict__ g, const float* __restrict__ bt,
                                                int width) {
    int row = blockIdx.x;
    const float* p = X + (size_t)row * width;
    float s = 0.f, s2 = 0.f;
    for (int i = threadIdx.x; i < width; i += 256) { float v = p[i]; s += v; s2 += v * v; }
    #pragma unroll
    for (int off = 32; off; off >>= 1) { s += __shfl_down(s, off); s2 += __shfl_down(s2, off); }
    __shared__ float red[4][2];
    int wv = threadIdx.x >> 6;
    if ((threadIdx.x & 63) == 0) { red[wv][0] = s; red[wv][1] = s2; }
    __syncthreads();
    if (threadIdx.x == 0) {
        float a = 0.f, b2 = 0.f;
        for (int i = 0; i < 4; ++i) { a += red[i][0]; b2 += red[i][1]; }
        float m = a / width;
        float var = fmaxf(b2 / width - m * m, 0.f);
        red[0][0] = m; red[0][1] = rsqrtf(var + 1e-5f);
    }
    __syncthreads();
    float m = red[0][0], rs = red[0][1];
    u16* q = Y + (size_t)row * width;
    for (int i = threadIdx.x; i < width; i += 256)
        q[i] = f2bf((p[i] - m) * rs * g[i] + bt[i]);
}

// ---------------- m97-style MFMA GEMM: C = A @ Bt^T, 128x128, BK=32, GLL staging ----------
__global__ __launch_bounds__(256) void gemm_bt(const u16* __restrict__ A, const u16* __restrict__ A2,
                                               int lda, const u16* __restrict__ Bt, int ldb,
                                               void* __restrict__ C, void* __restrict__ C2,
                                               int ldc, int nsplit,
                                               const float* __restrict__ bias, int relu, int K,
                                               int obf) {
    __shared__ u16 As[128 * 32];
    __shared__ u16 Bs[128 * 32];
    int tid  = threadIdx.x;
    int bm   = blockIdx.x * 128;
    int bn   = blockIdx.y * 128;
    const u16* Ab = A;
    void* Cb = C;
    int cn = bn;
    if (bn >= nsplit) { Ab = A2; Cb = C2; cn = bn - nsplit; }

    int lane = tid & 63;
    int wv   = tid >> 6;
    int quad = lane >> 4;
    int r    = lane & 15;
    int wm   = (wv >> 1) * 64;
    int wn   = (wv & 1) * 64;

    floatx4 acc[4][4];
    #pragma unroll
    for (int i = 0; i < 4; ++i)
        #pragma unroll
        for (int j = 0; j < 4; ++j)
            #pragma unroll
            for (int k = 0; k < 4; ++k) acc[i][j][k] = 0.f;

    int row0 = tid >> 2;
    int ks0  = (tid & 3) * 8;
    const u16* Abase  = Ab + (size_t)(bm + row0) * lda + ks0;
    const u16* Abase2 = Ab + (size_t)(bm + 64 + row0) * lda + ks0;
    const u16* Bbase  = Bt + (size_t)(bn + row0) * ldb + ks0;
    const u16* Bbase2 = Bt + (size_t)(bn + 64 + row0) * ldb + ks0;
    u16* AsD  = As + tid * 8;
    u16* AsD2 = As + 2048 + tid * 8;
    u16* BsD  = Bs + tid * 8;
    u16* BsD2 = Bs + 2048 + tid * 8;

    for (int k0 = 0; k0 < K; k0 += 32) {
        GLL(Abase + k0, AsD);
        GLL(Abase2 + k0, AsD2);
        GLL(Bbase + k0, BsD);
        GLL(Bbase2 + k0, BsD2);
        __syncthreads();
        short8 af[4], bf[4];
        #pragma unroll
        for (int mi = 0; mi < 4; ++mi) af[mi] = *(const short8*)&As[(wm + mi * 16 + r) * 32 + quad * 8];
        #pragma unroll
        for (int ni = 0; ni < 4; ++ni) bf[ni] = *(const short8*)&Bs[(wn + ni * 16 + r) * 32 + quad * 8];
        #pragma unroll
        for (int mi = 0; mi < 4; ++mi)
            #pragma unroll
            for (int ni = 0; ni < 4; ++ni)
                acc[mi][ni] = __builtin_amdgcn_mfma_f32_16x16x32_bf16(af[mi], bf[ni], acc[mi][ni], 0, 0, 0);
        __syncthreads();
    }

    #pragma unroll
    for (int mi = 0; mi < 4; ++mi)
        #pragma unroll
        for (int ni = 0; ni < 4; ++ni) {
            int col = cn + wn + ni * 16 + r;
            float bs = bias ? bias[col] : 0.f;
            #pragma unroll
            for (int reg = 0; reg < 4; ++reg) {
                int row = bm + wm + mi * 16 + quad * 4 + reg;
                float v = acc[mi][ni][reg] + bs;
                if (relu) v = fmaxf(v, 0.f);
                if (obf) ((u16*)Cb)[(size_t)row * ldc + col] = f2bf(v);
                else     ((float*)Cb)[(size_t)row * ldc + col] = v;
            }
        }
}

// ---------------- SRU scan: LDS double-buffered tile staging (m97 pattern) ----------------
// 128 blocks x 128 threads. Block: direction d = blk>>6, 128 consecutive chains (fixed b).
// Chunk = 256 steps as 16 tiles x 16 steps. Tile data (u0/fp/rp bf16 + x f32 per chain)
// staged via global_load_lds into 20KB buffer; compute reads LDS only; dbuf overlaps.
#define TC 256
__global__ __launch_bounds__(128) void scan_k(const u16* __restrict__ Uf, const u16* __restrict__ Ub,
                                              const float* __restrict__ Xp, float* __restrict__ Xn,
                                              float* __restrict__ cstate, const float* __restrict__ vv,
                                              const float* __restrict__ bb, int t0f, int t0b, int init) {
    __shared__ __align__(16) char lds[2][20480];  // 16 steps * 1280 B
    int tid = threadIdx.x;
    int d   = blockIdx.x >> 6;
    int c0  = (blockIdx.x & 63) * 128;
    int b   = c0 >> 9;
    int h0  = c0 & 511;
    int h   = h0 + tid;
    int gid = d * 8192 + c0 + tid;

    float v0 = vv[(d * 2 + 0) * 512 + h];
    float v1 = vv[(d * 2 + 1) * 512 + h];
    float b0 = bb[(d * 2 + 0) * 512 + h];
    float b1 = bb[(d * 2 + 1) * 512 + h];
    const u16* U = d ? Ub : Uf;
    int t0 = d ? t0b : t0f;
    float* ob = Xn + (size_t)b * 1024 + d * 512 + h;
    float cc = init ? 0.f : cstate[gid];

    // stage tile tk into buffer bw: 1280 units of 16B, 10 per thread
    auto stage = [&](int tk, int bw) {
        #pragma unroll
        for (int it = 0; it < 10; ++it) {
            int unit = it * 128 + tid;
            int s = unit / 80;
            int j = unit - s * 80;
            int gs = tk * 16 + s;
            int sl = d ? (TC - 1 - gs) : gs;
            const void* gp;
            if (j < 48) {
                int k = j >> 4, jj = j & 15;
                gp = U + ((size_t)(sl * 16 + b) * 1536 + k * 512 + h0 + jj * 8);
            } else {
                gp = Xp + ((size_t)(t0 + sl) * 16384 + b * 1024 + d * 512 + h0 + (j - 48) * 4);
            }
            GLL(gp, &lds[bw][unit * 16]);
        }
    };

    stage(0, 0);
    __syncthreads();
    int bufw = 0;
    for (int tk = 0; tk < 16; ++tk) {
        int bufr = bufw;
        if (tk < 15) { bufw ^= 1; stage(tk + 1, bufw); }
        const char* B = lds[bufr];
        #pragma unroll
        for (int s = 0; s < 16; ++s) {
            int gs = tk * 16 + s;
            int sl = d ? (TC - 1 - gs) : gs;
            const char* sb = B + s * 1280;
            float u0 = bf2f(*(const u16*)(sb + tid * 2));
            float fp = bf2f(*(const u16*)(sb + 256 + tid * 2)) + b0;
            float rp = bf2f(*(const u16*)(sb + 512 + tid * 2)) + b1;
            float xr = *(const float*)(sb + 768 + tid * 4);
            float f = 1.f / (1.f + __expf(-(fp + v0 * cc)));
            float r = 1.f / (1.f + __expf(-(rp + v1 * cc)));
            cc = f * cc + (1.f - f) * u0;
            float th = 1.f - 2.f / (__expf(2.f * cc) + 1.f);
            ob[(size_t)(t0 + sl) * 16384] = r * th + (1.f - r) * xr;
        }
        __syncthreads();
    }
    cstate[gid] = cc;
}

// ---------------- classifier head ----------------
__global__ __launch_bounds__(256) void cls2_k(const float* __restrict__ FC1, const float* __restrict__ W2,
                                              const float* __restrict__ b2, void* __restrict__ out,
                                              const int* __restrict__ flag) {
    int isf32 = *flag;
    int row = blockIdx.x * 4 + (threadIdx.x >> 6);
    int v   = threadIdx.x & 63;
    if (v >= 29) return;
    const float* p = FC1 + (size_t)row * 512;
    float acc = 0.f;
    for (int k = 0; k < 512; ++k) acc = fmaf(p[k], W2[k * 29 + v], acc);
    acc += b2[v];
    int t = row >> 4, b = row & 15;
    size_t oi = ((size_t)b * 512 + t) * 29 + v;
    if (isf32) ((float*)out)[oi] = acc;
    else       ((u16*)out)[oi]   = f2bf(acc);
}

// ---------------- launch ----------------
extern "C" void kernel_launch(void* const* d_in, const int* in_sizes, int n_in,
                              void* d_out, int out_size, void* d_ws, size_t ws_size,
                              hipStream_t stream) {
    const void* x      = d_in[0];
    const void* proj_w = d_in[11];
    const void* sru_w  = d_in[12];
    const void* cls_w1 = d_in[19];

    float* ws = (float*)d_ws;
    const size_t O_X    = 0;
    const size_t O_C    = 16777216;
    const size_t O_HA   = 25165824;
    const size_t O_SM   = 33850368;
    const size_t O_SR   = 34112512;
    const size_t O_CST  = 34374656;
    const size_t O_PARK = 34391040;
    const size_t O_FLAG = 34483488;
    const size_t TOTAL  = 34483504;   // 131.55 MiB
    if (ws_size < TOTAL * sizeof(float)) {
        fill_k<<<(out_size + 255) / 256, 256, 0, stream>>>((float*)d_out, out_size);
        return;
    }

    float* X   = ws + O_X;
    u16*   C   = (u16*)(ws + O_C);
    u16*   HA  = (u16*)(ws + O_HA);
    float* SM  = ws + O_SM;
    float* SR  = ws + O_SR;
    float* CST = ws + O_CST;
    float* PK  = ws + O_PARK;
    int*   FLG = (int*)(ws + O_FLAG);

    u16*   Abf = (u16*)(ws + O_C);
    u16*   BtP = (u16*)(ws + 0);
    float* XP0 = ws + 25165824;
    u16*   XL  = (u16*)(ws + 0);
    float* XP1 = ws + 4194304;
    u16*   Uf  = (u16*)(ws + 12582912);
    u16*   Ub  = (u16*)(ws + 15728640);
    u16*   BtS = (u16*)(ws + 18874368);
    u16*   BtC = (u16*)(ws + O_SM);
    float* FC1 = ws + 12582912;

    float* p_cnn_w = PK + 0;      float* p_cnn_b = PK + 288;
    float* p_rw1   = PK + 320;    float* p_rb1   = PK + 27968;
    float* p_rw2   = PK + 28064;  float* p_rb2   = PK + 55712;
    float* p_l1g   = PK + 55808;  float* p_l1b   = PK + 56000;
    float* p_l2g   = PK + 56192;  float* p_l2b   = PK + 56384;
    float* p_sv    = PK + 56576;  float* p_sb    = PK + 62720;
    float* p_slng  = PK + 68864;  float* p_slnb  = PK + 71936;
    float* p_clng  = PK + 75008;  float* p_clnb  = PK + 76032;
    float* p_cb1   = PK + 77056;  float* p_cw2   = PK + 77568;
    float* p_cb2   = PK + 92416;

    sniff_k<<<1, 256, 0, stream>>>((const u16*)x, FLG);

    CvtArgs ca;
    const int srcidx[19] = {1,2,3,4,5,6,7,8,9,10,13,14,15,16,17,18,20,21,22};
    const int lens[19]   = {288,32,27648,96,27648,96,192,192,192,192,6144,6144,3072,3072,1024,1024,512,14848,29};
    const int offs[19]   = {0,288,320,27968,28064,55712,55808,56000,56192,56384,56576,62720,68864,71936,75008,76032,77056,77568,92416};
    for (int i = 0; i < 19; ++i) { ca.src[i] = d_in[srcidx[i]]; ca.len[i] = lens[i]; ca.off[i] = offs[i]; }
    cvtall_k<<<dim3(108, 19), 256, 0, stream>>>(ca, PK, FLG);

    zero_k<<<2048, 256, 0, stream>>>((float4*)HA, 2171136);
    conv1_k<<<16384, 256, 0, stream>>>(x, p_cnn_w, p_cnn_b, X, FLG);

    for (int i = 0; i < 3; ++i) {
        stats_k<<<1024, 256, 0, stream>>>(X, 0, SM, SR);
        apply_k<<<dim3(64, 16), 256, 0, stream>>>(X, 0, SM, SR, p_l1g + i * 64, p_l1b + i * 64, HA);
        convm_k<<<dim3(16, 8, 16), 256, 0, stream>>>(HA, C, p_rw1 + i * 9216, p_rb1 + i * 32, nullptr);
        stats_k<<<1024, 256, 0, stream>>>(C, 1, SM, SR);
        apply_k<<<dim3(64, 16), 256, 0, stream>>>(C, 1, SM, SR, p_l2g + i * 64, p_l2b + i * 64, HA);
        convm_k<<<dim3(16, 8, 16), 256, 0, stream>>>(HA, X, p_rw2 + i * 9216, p_rb2 + i * 32, X);
    }

    transpose_k<<<dim3(8, 32, 16), 256, 0, stream>>>(X, Abf);
    wtr_k<<<dim3(32, 16), 256, 0, stream>>>(proj_w, 1024, 0, BtP, 2048, FLG);
    gemm_bt<<<dim3(64, 8), 256, 0, stream>>>(Abf, Abf, 2048, BtP, 2048, XP0, XP0, 1024,
                                             1 << 30, nullptr, 0, 2048, 0);

    for (int l = 0; l < 3; ++l)
        wtr_k<<<dim3(16, 48), 256, 0, stream>>>(sru_w, 3072, (size_t)l * 3145728,
                                                BtS + (size_t)l * 3145728, 1024, FLG);
    wtr_k<<<dim3(16, 8), 256, 0, stream>>>(cls_w1, 512, 0, BtC, 1024, FLG);

    float* cur = XP0;
    float* nxt = XP1;
    for (int l = 0; l < 3; ++l) {
        lnlast_k<<<8192, 256, 0, stream>>>(cur, XL, p_slng + l * 1024, p_slnb + l * 1024, 1024);
        const u16* Btl = BtS + (size_t)l * 3145728;
        for (int j = 0; j < 2; ++j) {
            int t0f = j * TC;
            int t0b = (1 - j) * TC;
            gemm_bt<<<dim3(32, 24), 256, 0, stream>>>(XL + (size_t)t0f * 16 * 1024,
                                                      XL + (size_t)t0b * 16 * 1024, 1024,
                                                      Btl, 1024, Uf, Ub, 1536, 1536,
                                                      nullptr, 0, 1024, 1);
            scan_k<<<128, 128, 0, stream>>>(Uf, Ub, cur, nxt, CST,
                                            p_sv + l * 2048, p_sb + l * 2048, t0f, t0b, j == 0);
        }
        float* tmp = cur; cur = nxt; nxt = tmp;
    }

    lnlast_k<<<8192, 256, 0, stream>>>(cur, XL, p_clng, p_clnb, 1024);
    gemm_bt<<<dim3(64, 4), 256, 0, stream>>>(XL, XL, 1024, BtC, 1024, FC1, FC1, 512,
                                             1 << 30, p_cb1, 1, 1024, 0);
    cls2_k<<<2048, 256, 0, stream>>>(FC1, p_cw2, p_cb2, d_out, FLG);
}

// Round 10
// 1543.541 us; speedup vs baseline: 1.3941x; 1.0289x over previous
//
#include <hip/hip_runtime.h>

typedef unsigned short u16;
typedef unsigned int u32;
typedef __attribute__((ext_vector_type(8))) short short8;
typedef __attribute__((ext_vector_type(4))) float floatx4;

__device__ __forceinline__ float bf2f(u16 u) {
    union { unsigned int i; float f; } v; v.i = ((unsigned int)u) << 16; return v.f;
}
__device__ __forceinline__ u16 f2bf(float f) {
    union { float f; unsigned int i; } v; v.f = f;
    unsigned int i = v.i + 0x7fffu + ((v.i >> 16) & 1u);  // RNE
    return (u16)(i >> 16);
}

// async global->LDS, 16B per lane; LDS dest must be wave-uniform base + lane*16
#define GLL(g, l) __builtin_amdgcn_global_load_lds( \
    (const __attribute__((address_space(1))) void*)(g), \
    (__attribute__((address_space(3))) void*)(l), 16, 0, 0)

// Ha halo tensor: [b][f_idx 0..65][t_idx 0..513 (pad 514)][ci 0..31] bf16
#define HA_BSTRIDE 1085568  // 66*514*32

// ---------------- dtype sniffer: flag=1 means inputs are float32 ----------------
__global__ __launch_bounds__(256) void sniff_k(const u16* __restrict__ x, int* __restrict__ flag) {
    __shared__ int red[4];
    int cnt = 0;
    for (int i = 0; i < 16; ++i) {
        u16 v = x[(threadIdx.x * 16 + i) * 2];
        int e = (v >> 7) & 0xFF;
        if (e >= 110 && e <= 135) cnt++;
    }
    #pragma unroll
    for (int off = 32; off; off >>= 1) cnt += __shfl_down(cnt, off);
    if ((threadIdx.x & 63) == 0) red[threadIdx.x >> 6] = cnt;
    __syncthreads();
    if (threadIdx.x == 0) {
        int tot = red[0] + red[1] + red[2] + red[3];
        *flag = (tot < 2048) ? 1 : 0;
    }
}

__device__ __forceinline__ float ldin(const void* p, size_t i, int isf32) {
    return isf32 ? ((const float*)p)[i] : bf2f(((const u16*)p)[i]);
}

// ---------------- canonicalize all params to f32 park (one launch) ----------------
struct CvtArgs {
    const void* src[19];
    int len[19];
    int off[19];
};
__global__ __launch_bounds__(256) void cvtall_k(CvtArgs a, float* __restrict__ dst,
                                                const int* __restrict__ flag) {
    int isf32 = *flag;
    int seg = blockIdx.y;
    int n = a.len[seg];
    const void* s = a.src[seg];
    float* d = dst + a.off[seg];
    for (int i = blockIdx.x * 256 + threadIdx.x; i < n; i += gridDim.x * 256)
        d[i] = ldin(s, i, isf32);
}

// ---------------- weight transpose: W[K][N] (dual dtype) -> Wt[N][K] bf16 ----------------
__global__ __launch_bounds__(256) void wtr_k(const void* __restrict__ W, int ldw, size_t wofs,
                                             u16* __restrict__ Wt, int ldt,
                                             const int* __restrict__ flag) {
    int isf32 = *flag;
    __shared__ u16 t[64][65];
    int k0 = blockIdx.x * 64, n0 = blockIdx.y * 64;
    int tid = threadIdx.x;
    #pragma unroll
    for (int i = 0; i < 16; ++i) {
        int kk = i * 4 + (tid >> 6), nn = tid & 63;
        t[kk][nn] = f2bf(ldin(W, wofs + (size_t)(k0 + kk) * ldw + n0 + nn, isf32));
    }
    __syncthreads();
    #pragma unroll
    for (int i = 0; i < 16; ++i) {
        int nn = i * 4 + (tid >> 6), kk = tid & 63;
        Wt[(size_t)(n0 + nn) * ldt + k0 + kk] = t[kk][nn];
    }
}

// ---------------- zero / guard fill ----------------
__global__ __launch_bounds__(256) void zero_k(float4* __restrict__ p, int n4) {
    float4 z = {0.f, 0.f, 0.f, 0.f};
    for (int i = blockIdx.x * 256 + threadIdx.x; i < n4; i += gridDim.x * 256) p[i] = z;
}
__global__ __launch_bounds__(256) void fill_k(float* __restrict__ p, int n) {
    int i = blockIdx.x * 256 + threadIdx.x;
    if (i < n) p[i] = 1.0e6f;
}

// ---------------- conv stem: 1->32, k3 s2 p1 -> X f32 NCHW; 4 co per thread ----------------
__global__ __launch_bounds__(256) void conv1_k(const void* __restrict__ x, const float* __restrict__ w,
                                               const float* __restrict__ bias, float* __restrict__ out,
                                               const int* __restrict__ flag) {
    int isf32 = *flag;
    int idx = blockIdx.x * 256 + threadIdx.x;   // 4,194,304 threads
    int t  = idx & 511;
    int f  = (idx >> 9) & 63;
    int cg = (idx >> 15) & 7;       // co = cg*4 + i
    int b  = idx >> 18;
    size_t xb = (size_t)b * 128 * 1024;

    float wr[4][9];
    #pragma unroll
    for (int i = 0; i < 4; ++i)
        #pragma unroll
        for (int k = 0; k < 9; ++k) wr[i][k] = w[(cg * 4 + i) * 9 + k];

    float acc[4];
    #pragma unroll
    for (int i = 0; i < 4; ++i) acc[i] = bias[cg * 4 + i];

    #pragma unroll
    for (int df = 0; df < 3; ++df) {
        int fi = 2 * f + df - 1;
        if (fi < 0 || fi >= 128) continue;       // wave-uniform branch
        size_t rowb = xb + (size_t)fi * 1024;
        float xv[3];
        #pragma unroll
        for (int dt = 0; dt < 3; ++dt) {
            int ti = 2 * t + dt - 1;
            float v = 0.f;
            if (ti >= 0 && ti < 1024) v = ldin(x, rowb + ti, isf32);
            xv[dt] = v;
        }
        #pragma unroll
        for (int i = 0; i < 4; ++i)
            #pragma unroll
            for (int dt = 0; dt < 3; ++dt)
                acc[i] = fmaf(wr[i][df * 3 + dt], xv[dt], acc[i]);
    }
    size_t obase = (((size_t)b * 32 + cg * 4) * 64 + f) * 512 + t;
    #pragma unroll
    for (int i = 0; i < 4; ++i) out[obase + (size_t)i * 64 * 512] = acc[i];
}

// ---------------- LN-over-f stats (dual-dtype input, NCHW) ----------------
__global__ __launch_bounds__(256) void stats_k(const void* __restrict__ X, int isbf,
                                               float* __restrict__ sm, float* __restrict__ sr) {
    int idx = blockIdx.x * 256 + threadIdx.x;  // 16*32*512
    int t  = idx & 511;
    int bc = idx >> 9;
    size_t base = (size_t)bc * 64 * 512 + t;
    float s = 0.f, s2 = 0.f;
    #pragma unroll 8
    for (int f = 0; f < 64; ++f) {
        float v = isbf ? bf2f(((const u16*)X)[base + f * 512]) : ((const float*)X)[base + f * 512];
        s += v; s2 += v * v;
    }
    float m  = s * (1.f / 64.f);
    float var = fmaxf(s2 * (1.f / 64.f) - m * m, 0.f);
    sm[idx] = m;
    sr[idx] = rsqrtf(var + 1e-5f);
}

// ---------------- apply LN+ReLU: NCHW (f32|bf16) -> Ha NHWC halo bf16 ----------------
__global__ __launch_bounds__(256) void apply_k(const void* __restrict__ in, int isbf,
                                               const float* __restrict__ sm, const float* __restrict__ sr,
                                               const float* __restrict__ g, const float* __restrict__ be,
                                               u16* __restrict__ Ha) {
    int f = blockIdx.x;
    int b = blockIdx.y;
    float gg = g[f], bb_ = be[f];
    for (int it = 0; it < 2; ++it) {
        int t = it * 256 + threadIdx.x;
        u32 pk[16];
        #pragma unroll
        for (int cp = 0; cp < 16; ++cp) {
            u32 w = 0;
            #pragma unroll
            for (int half = 0; half < 2; ++half) {
                int ci = cp * 2 + half;
                size_t xi = (((size_t)b * 32 + ci) * 64 + f) * 512 + t;
                float xv = isbf ? bf2f(((const u16*)in)[xi]) : ((const float*)in)[xi];
                int si = (b * 32 + ci) * 512 + t;
                float hv = fmaxf((xv - sm[si]) * sr[si] * gg + bb_, 0.f);
                w |= ((u32)f2bf(hv)) << (half * 16);
            }
            pk[cp] = w;
        }
        u32* orow = (u32*)(Ha + (size_t)b * HA_BSTRIDE + ((size_t)(f + 1) * 514 + (t + 1)) * 32);
        #pragma unroll
        for (int q = 0; q < 16; ++q) orow[q] = pk[q];
    }
}

// ---------------- conv32 k3 s1 p1 via MFMA, GLL staging from Ha ----------------
// f-tile 32 (halo 34), t-tile 16 (halo 18). grid (2 f, 32 t, 16 b), 256 thr = 4 waves;
// wave wv covers local f [wv*8, wv*8+8) as 2 sub-tiles of 4.
__global__ __launch_bounds__(256) void convm_k(const u16* __restrict__ Ha, void* __restrict__ out,
                                               const float* __restrict__ w, const float* __restrict__ bias,
                                               const float* __restrict__ res) {
    __shared__ u16 act[34 * 18 * 32];  // 39168 B  [fp][tp][ci]
    int F0 = blockIdx.x * 32;
    int t0 = blockIdx.y * 16;
    int b  = blockIdx.z;
    const u16* Hb = Ha + (size_t)b * HA_BSTRIDE;
    int tid  = threadIdx.x;
    int lane = tid & 63;
    int wv   = tid >> 6;
    int quad = lane >> 4;
    int r    = lane & 15;

    // stage: 34*18*4 = 2448 units of 16B; LDS linear order == unit order
    #pragma unroll
    for (int it = 0; it < 10; ++it) {
        int u = it * 256 + tid;
        if (u < 2448) {
            int fp  = u / 72;           // 0..33
            int rem = u - fp * 72;
            int tp  = rem >> 2;         // 0..17
            int q   = rem & 3;
            GLL(Hb + ((size_t)(F0 + fp) * 514 + (t0 + tp)) * 32 + q * 8, act + u * 8);
        }
    }

    // B-fragments from park f32 weights (overlaps GLL)
    short8 bfrag[3][3][2];
    #pragma unroll
    for (int df = 0; df < 3; ++df)
        #pragma unroll
        for (int dt = 0; dt < 3; ++dt)
            #pragma unroll
            for (int ct = 0; ct < 2; ++ct) {
                short8 v;
                #pragma unroll
                for (int j = 0; j < 8; ++j) {
                    int co = ct * 16 + r, ci = quad * 8 + j;
                    v[j] = (short)f2bf(w[(co * 32 + ci) * 9 + df * 3 + dt]);
                }
                bfrag[df][dt][ct] = v;
            }
    __syncthreads();

    #pragma unroll
    for (int sub = 0; sub < 2; ++sub) {
        floatx4 acc[4][2];
        #pragma unroll
        for (int i = 0; i < 4; ++i)
            #pragma unroll
            for (int j = 0; j < 2; ++j)
                #pragma unroll
                for (int k = 0; k < 4; ++k) acc[i][j][k] = 0.f;

        int fb = wv * 8 + sub * 4;     // local f base, 0..28
        #pragma unroll
        for (int fh = 0; fh < 6; ++fh) {
            short8 af[3];
            #pragma unroll
            for (int dt = 0; dt < 3; ++dt)
                af[dt] = *(const short8*)&act[(((fb + fh) * 18) + (r + dt)) * 32 + quad * 8];
            #pragma unroll
            for (int df = 0; df < 3; ++df) {
                int rel = fh - df;
                if (rel < 0 || rel >= 4) continue;
                #pragma unroll
                for (int dt = 0; dt < 3; ++dt)
                    #pragma unroll
                    for (int ct = 0; ct < 2; ++ct)
                        acc[rel][ct] = __builtin_amdgcn_mfma_f32_16x16x32_bf16(
                            af[dt], bfrag[df][dt][ct], acc[rel][ct], 0, 0, 0);
            }
        }

        int tt = t0 + quad * 4;
        #pragma unroll
        for (int rel = 0; rel < 4; ++rel)
            #pragma unroll
            for (int ct = 0; ct < 2; ++ct) {
                int f  = F0 + fb + rel;
                int co = ct * 16 + r;
                size_t base = (((size_t)b * 32 + co) * 64 + f) * 512 + tt;
                float bs = bias[co];
                if (res) {
                    float4 rv = *(const float4*)(res + base);
                    float4 o;
                    o.x = acc[rel][ct][0] + bs + rv.x;
                    o.y = acc[rel][ct][1] + bs + rv.y;
                    o.z = acc[rel][ct][2] + bs + rv.z;
                    o.w = acc[rel][ct][3] + bs + rv.w;
                    *(float4*)((float*)out + base) = o;
                } else {
                    ushort4 o;
                    o.x = f2bf(acc[rel][ct][0] + bs);
                    o.y = f2bf(acc[rel][ct][1] + bs);
                    o.z = f2bf(acc[rel][ct][2] + bs);
                    o.w = f2bf(acc[rel][ct][3] + bs);
                    *(ushort4*)((u16*)out + base) = o;
                }
            }
    }
}

// ---------------- transpose X (b,c,f,t) f32 -> A[(t*16+b)][(c*64+f)] bf16 ----------------
__global__ __launch_bounds__(256) void transpose_k(const float* __restrict__ X, u16* __restrict__ A) {
    __shared__ float tile[64][65];
    int t0 = blockIdx.x * 64;
    int c  = blockIdx.y;
    int b  = blockIdx.z;
    const float* p = X + (((size_t)b * 32 + c) * 64) * 512 + t0;
    #pragma unroll
    for (int i = 0; i < 16; ++i) {
        int f = i * 4 + (threadIdx.x >> 6);
        int t = threadIdx.x & 63;
        tile[f][t] = p[(size_t)f * 512 + t];
    }
    __syncthreads();
    #pragma unroll
    for (int i = 0; i < 16; ++i) {
        int t = i * 4 + (threadIdx.x >> 6);
        int f = threadIdx.x & 63;
        A[((size_t)(t0 + t) * 16 + b) * 2048 + c * 64 + f] = f2bf(tile[f][t]);
    }
}

// ---------------- row layernorm, f32 in -> bf16 out ----------------
__global__ __launch_bounds__(256) void lnlast_k(const float* __restrict__ X, u16* __restrict__ Y,
                                                const float* __restrict__ g, const float* __restrict__ bt,
                                                int width) {
    int row = blockIdx.x;
    const float* p = X + (size_t)row * width;
    float s = 0.f, s2 = 0.f;
    for (int i = threadIdx.x; i < width; i += 256) { float v = p[i]; s += v; s2 += v * v; }
    #pragma unroll
    for (int off = 32; off; off >>= 1) { s += __shfl_down(s, off); s2 += __shfl_down(s2, off); }
    __shared__ float red[4][2];
    int wv = threadIdx.x >> 6;
    if ((threadIdx.x & 63) == 0) { red[wv][0] = s; red[wv][1] = s2; }
    __syncthreads();
    if (threadIdx.x == 0) {
        float a = 0.f, b2 = 0.f;
        for (int i = 0; i < 4; ++i) { a += red[i][0]; b2 += red[i][1]; }
        float m = a / width;
        float var = fmaxf(b2 / width - m * m, 0.f);
        red[0][0] = m; red[0][1] = rsqrtf(var + 1e-5f);
    }
    __syncthreads();
    float m = red[0][0], rs = red[0][1];
    u16* q = Y + (size_t)row * width;
    for (int i = threadIdx.x; i < width; i += 256)
        q[i] = f2bf((p[i] - m) * rs * g[i] + bt[i]);
}

// ---------------- m97-style MFMA GEMM: C = A @ Bt^T, 128x128, BK=32, GLL staging ----------
__global__ __launch_bounds__(256) void gemm_bt(const u16* __restrict__ A, const u16* __restrict__ A2,
                                               int lda, const u16* __restrict__ Bt, int ldb,
                                               void* __restrict__ C, void* __restrict__ C2,
                                               int ldc, int nsplit,
                                               const float* __restrict__ bias, int relu, int K,
                                               int obf) {
    __shared__ u16 As[128 * 32];
    __shared__ u16 Bs[128 * 32];
    int tid  = threadIdx.x;
    int bm   = blockIdx.x * 128;
    int bn   = blockIdx.y * 128;
    const u16* Ab = A;
    void* Cb = C;
    int cn = bn;
    if (bn >= nsplit) { Ab = A2; Cb = C2; cn = bn - nsplit; }

    int lane = tid & 63;
    int wv   = tid >> 6;
    int quad = lane >> 4;
    int r    = lane & 15;
    int wm   = (wv >> 1) * 64;
    int wn   = (wv & 1) * 64;

    floatx4 acc[4][4];
    #pragma unroll
    for (int i = 0; i < 4; ++i)
        #pragma unroll
        for (int j = 0; j < 4; ++j)
            #pragma unroll
            for (int k = 0; k < 4; ++k) acc[i][j][k] = 0.f;

    int row0 = tid >> 2;
    int ks0  = (tid & 3) * 8;
    const u16* Abase  = Ab + (size_t)(bm + row0) * lda + ks0;
    const u16* Abase2 = Ab + (size_t)(bm + 64 + row0) * lda + ks0;
    const u16* Bbase  = Bt + (size_t)(bn + row0) * ldb + ks0;
    const u16* Bbase2 = Bt + (size_t)(bn + 64 + row0) * ldb + ks0;
    u16* AsD  = As + tid * 8;
    u16* AsD2 = As + 2048 + tid * 8;
    u16* BsD  = Bs + tid * 8;
    u16* BsD2 = Bs + 2048 + tid * 8;

    for (int k0 = 0; k0 < K; k0 += 32) {
        GLL(Abase + k0, AsD);
        GLL(Abase2 + k0, AsD2);
        GLL(Bbase + k0, BsD);
        GLL(Bbase2 + k0, BsD2);
        __syncthreads();
        short8 af[4], bf[4];
        #pragma unroll
        for (int mi = 0; mi < 4; ++mi) af[mi] = *(const short8*)&As[(wm + mi * 16 + r) * 32 + quad * 8];
        #pragma unroll
        for (int ni = 0; ni < 4; ++ni) bf[ni] = *(const short8*)&Bs[(wn + ni * 16 + r) * 32 + quad * 8];
        #pragma unroll
        for (int mi = 0; mi < 4; ++mi)
            #pragma unroll
            for (int ni = 0; ni < 4; ++ni)
                acc[mi][ni] = __builtin_amdgcn_mfma_f32_16x16x32_bf16(af[mi], bf[ni], acc[mi][ni], 0, 0, 0);
        __syncthreads();
    }

    #pragma unroll
    for (int mi = 0; mi < 4; ++mi)
        #pragma unroll
        for (int ni = 0; ni < 4; ++ni) {
            int col = cn + wn + ni * 16 + r;
            float bs = bias ? bias[col] : 0.f;
            #pragma unroll
            for (int reg = 0; reg < 4; ++reg) {
                int row = bm + wm + mi * 16 + quad * 4 + reg;
                float v = acc[mi][ni][reg] + bs;
                if (relu) v = fmaxf(v, 0.f);
                if (obf) ((u16*)Cb)[(size_t)row * ldc + col] = f2bf(v);
                else     ((float*)Cb)[(size_t)row * ldc + col] = v;
            }
        }
}

// ---------------- SRU scan: LDS double-buffered tile staging (m97 pattern) ----------------
#define TC 256
__global__ __launch_bounds__(128) void scan_k(const u16* __restrict__ Uf, const u16* __restrict__ Ub,
                                              const float* __restrict__ Xp, float* __restrict__ Xn,
                                              float* __restrict__ cstate, const float* __restrict__ vv,
                                              const float* __restrict__ bb, int t0f, int t0b, int init) {
    __shared__ __align__(16) char lds[2][20480];  // 16 steps * 1280 B
    int tid = threadIdx.x;
    int d   = blockIdx.x >> 6;
    int c0  = (blockIdx.x & 63) * 128;
    int b   = c0 >> 9;
    int h0  = c0 & 511;
    int h   = h0 + tid;
    int gid = d * 8192 + c0 + tid;

    float v0 = vv[(d * 2 + 0) * 512 + h];
    float v1 = vv[(d * 2 + 1) * 512 + h];
    float b0 = bb[(d * 2 + 0) * 512 + h];
    float b1 = bb[(d * 2 + 1) * 512 + h];
    const u16* U = d ? Ub : Uf;
    int t0 = d ? t0b : t0f;
    float* ob = Xn + (size_t)b * 1024 + d * 512 + h;
    float cc = init ? 0.f : cstate[gid];

    auto stage = [&](int tk, int bw) {
        #pragma unroll
        for (int it = 0; it < 10; ++it) {
            int unit = it * 128 + tid;
            int s = unit / 80;
            int j = unit - s * 80;
            int gs = tk * 16 + s;
            int sl = d ? (TC - 1 - gs) : gs;
            const void* gp;
            if (j < 48) {
                int k = j >> 4, jj = j & 15;
                gp = U + ((size_t)(sl * 16 + b) * 1536 + k * 512 + h0 + jj * 8);
            } else {
                gp = Xp + ((size_t)(t0 + sl) * 16384 + b * 1024 + d * 512 + h0 + (j - 48) * 4);
            }
            GLL(gp, &lds[bw][unit * 16]);
        }
    };

    stage(0, 0);
    __syncthreads();
    int bufw = 0;
    for (int tk = 0; tk < 16; ++tk) {
        int bufr = bufw;
        if (tk < 15) { bufw ^= 1; stage(tk + 1, bufw); }
        const char* B = lds[bufr];
        #pragma unroll
        for (int s = 0; s < 16; ++s) {
            int gs = tk * 16 + s;
            int sl = d ? (TC - 1 - gs) : gs;
            const char* sb = B + s * 1280;
            float u0 = bf2f(*(const u16*)(sb + tid * 2));
            float fp = bf2f(*(const u16*)(sb + 256 + tid * 2)) + b0;
            float rp = bf2f(*(const u16*)(sb + 512 + tid * 2)) + b1;
            float xr = *(const float*)(sb + 768 + tid * 4);
            float f = 1.f / (1.f + __expf(-(fp + v0 * cc)));
            float r = 1.f / (1.f + __expf(-(rp + v1 * cc)));
            cc = f * cc + (1.f - f) * u0;
            float th = 1.f - 2.f / (__expf(2.f * cc) + 1.f);
            ob[(size_t)(t0 + sl) * 16384] = r * th + (1.f - r) * xr;
        }
        __syncthreads();
    }
    cstate[gid] = cc;
}

// ---------------- classifier head ----------------
__global__ __launch_bounds__(256) void cls2_k(const float* __restrict__ FC1, const float* __restrict__ W2,
                                              const float* __restrict__ b2, void* __restrict__ out,
                                              const int* __restrict__ flag) {
    int isf32 = *flag;
    int row = blockIdx.x * 4 + (threadIdx.x >> 6);
    int v   = threadIdx.x & 63;
    if (v >= 29) return;
    const float* p = FC1 + (size_t)row * 512;
    float acc = 0.f;
    for (int k = 0; k < 512; ++k) acc = fmaf(p[k], W2[k * 29 + v], acc);
    acc += b2[v];
    int t = row >> 4, b = row & 15;
    size_t oi = ((size_t)b * 512 + t) * 29 + v;
    if (isf32) ((float*)out)[oi] = acc;
    else       ((u16*)out)[oi]   = f2bf(acc);
}

// ---------------- launch ----------------
extern "C" void kernel_launch(void* const* d_in, const int* in_sizes, int n_in,
                              void* d_out, int out_size, void* d_ws, size_t ws_size,
                              hipStream_t stream) {
    const void* x      = d_in[0];
    const void* proj_w = d_in[11];
    const void* sru_w  = d_in[12];
    const void* cls_w1 = d_in[19];

    float* ws = (float*)d_ws;
    const size_t O_X    = 0;
    const size_t O_C    = 16777216;
    const size_t O_HA   = 25165824;
    const size_t O_SM   = 33850368;
    const size_t O_SR   = 34112512;
    const size_t O_CST  = 34374656;
    const size_t O_PARK = 34391040;
    const size_t O_FLAG = 34483488;
    const size_t TOTAL  = 34483504;   // 131.55 MiB
    if (ws_size < TOTAL * sizeof(float)) {
        fill_k<<<(out_size + 255) / 256, 256, 0, stream>>>((float*)d_out, out_size);
        return;
    }

    float* X   = ws + O_X;
    u16*   C   = (u16*)(ws + O_C);
    u16*   HA  = (u16*)(ws + O_HA);
    float* SM  = ws + O_SM;
    float* SR  = ws + O_SR;
    float* CST = ws + O_CST;
    float* PK  = ws + O_PARK;
    int*   FLG = (int*)(ws + O_FLAG);

    u16*   Abf = (u16*)(ws + O_C);
    u16*   BtP = (u16*)(ws + 0);
    float* XP0 = ws + 25165824;
    u16*   XL  = (u16*)(ws + 0);
    float* XP1 = ws + 4194304;
    u16*   Uf  = (u16*)(ws + 12582912);
    u16*   Ub  = (u16*)(ws + 15728640);
    u16*   BtS = (u16*)(ws + 18874368);
    u16*   BtC = (u16*)(ws + O_SM);
    float* FC1 = ws + 12582912;

    float* p_cnn_w = PK + 0;      float* p_cnn_b = PK + 288;
    float* p_rw1   = PK + 320;    float* p_rb1   = PK + 27968;
    float* p_rw2   = PK + 28064;  float* p_rb2   = PK + 55712;
    float* p_l1g   = PK + 55808;  float* p_l1b   = PK + 56000;
    float* p_l2g   = PK + 56192;  float* p_l2b   = PK + 56384;
    float* p_sv    = PK + 56576;  float* p_sb    = PK + 62720;
    float* p_slng  = PK + 68864;  float* p_slnb  = PK + 71936;
    float* p_clng  = PK + 75008;  float* p_clnb  = PK + 76032;
    float* p_cb1   = PK + 77056;  float* p_cw2   = PK + 77568;
    float* p_cb2   = PK + 92416;

    sniff_k<<<1, 256, 0, stream>>>((const u16*)x, FLG);

    CvtArgs ca;
    const int srcidx[19] = {1,2,3,4,5,6,7,8,9,10,13,14,15,16,17,18,20,21,22};
    const int lens[19]   = {288,32,27648,96,27648,96,192,192,192,192,6144,6144,3072,3072,1024,1024,512,14848,29};
    const int offs[19]   = {0,288,320,27968,28064,55712,55808,56000,56192,56384,56576,62720,68864,71936,75008,76032,77056,77568,92416};
    for (int i = 0; i < 19; ++i) { ca.src[i] = d_in[srcidx[i]]; ca.len[i] = lens[i]; ca.off[i] = offs[i]; }
    cvtall_k<<<dim3(108, 19), 256, 0, stream>>>(ca, PK, FLG);

    zero_k<<<2048, 256, 0, stream>>>((float4*)HA, 2171136);
    conv1_k<<<16384, 256, 0, stream>>>(x, p_cnn_w, p_cnn_b, X, FLG);

    for (int i = 0; i < 3; ++i) {
        stats_k<<<1024, 256, 0, stream>>>(X, 0, SM, SR);
        apply_k<<<dim3(64, 16), 256, 0, stream>>>(X, 0, SM, SR, p_l1g + i * 64, p_l1b + i * 64, HA);
        convm_k<<<dim3(2, 32, 16), 256, 0, stream>>>(HA, C, p_rw1 + i * 9216, p_rb1 + i * 32, nullptr);
        stats_k<<<1024, 256, 0, stream>>>(C, 1, SM, SR);
        apply_k<<<dim3(64, 16), 256, 0, stream>>>(C, 1, SM, SR, p_l2g + i * 64, p_l2b + i * 64, HA);
        convm_k<<<dim3(2, 32, 16), 256, 0, stream>>>(HA, X, p_rw2 + i * 9216, p_rb2 + i * 32, X);
    }

    transpose_k<<<dim3(8, 32, 16), 256, 0, stream>>>(X, Abf);
    wtr_k<<<dim3(32, 16), 256, 0, stream>>>(proj_w, 1024, 0, BtP, 2048, FLG);
    gemm_bt<<<dim3(64, 8), 256, 0, stream>>>(Abf, Abf, 2048, BtP, 2048, XP0, XP0, 1024,
                                             1 << 30, nullptr, 0, 2048, 0);

    for (int l = 0; l < 3; ++l)
        wtr_k<<<dim3(16, 48), 256, 0, stream>>>(sru_w, 3072, (size_t)l * 3145728,
                                                BtS + (size_t)l * 3145728, 1024, FLG);
    wtr_k<<<dim3(16, 8), 256, 0, stream>>>(cls_w1, 512, 0, BtC, 1024, FLG);

    float* cur = XP0;
    float* nxt = XP1;
    for (int l = 0; l < 3; ++l) {
        lnlast_k<<<8192, 256, 0, stream>>>(cur, XL, p_slng + l * 1024, p_slnb + l * 1024, 1024);
        const u16* Btl = BtS + (size_t)l * 3145728;
        for (int j = 0; j < 2; ++j) {
            int t0f = j * TC;
            int t0b = (1 - j) * TC;
            gemm_bt<<<dim3(32, 24), 256, 0, stream>>>(XL + (size_t)t0f * 16 * 1024,
                                                      XL + (size_t)t0b * 16 * 1024, 1024,
                                                      Btl, 1024, Uf, Ub, 1536, 1536,
                                                      nullptr, 0, 1024, 1);
            scan_k<<<128, 128, 0, stream>>>(Uf, Ub, cur, nxt, CST,
                                            p_sv + l * 2048, p_sb + l * 2048, t0f, t0b, j == 0);
        }
        float* tmp = cur; cur = nxt; nxt = tmp;
    }

    lnlast_k<<<8192, 256, 0, stream>>>(cur, XL, p_clng, p_clnb, 1024);
    gemm_bt<<<dim3(64, 4), 256, 0, stream>>>(XL, XL, 1024, BtC, 1024, FC1, FC1, 512,
                                             1 << 30, p_cb1, 1, 1024, 0);
    cls2_k<<<2048, 256, 0, stream>>>(FC1, p_cw2, p_cb2, d_out, FLG);
}

// Round 12
// 1529.034 us; speedup vs baseline: 1.4073x; 1.0095x over previous
//
#include <hip/hip_runtime.h>

typedef unsigned short u16;
typedef unsigned int u32;
typedef __attribute__((ext_vector_type(8))) short short8;
typedef __attribute__((ext_vector_type(4))) float floatx4;

__device__ __forceinline__ float bf2f(u16 u) {
    union { unsigned int i; float f; } v; v.i = ((unsigned int)u) << 16; return v.f;
}
__device__ __forceinline__ u16 f2bf(float f) {
    union { float f; unsigned int i; } v; v.f = f;
    unsigned int i = v.i + 0x7fffu + ((v.i >> 16) & 1u);  // RNE
    return (u16)(i >> 16);
}

// async global->LDS, 16B per lane; LDS dest must be wave-uniform base + lane*16
#define GLL(g, l) __builtin_amdgcn_global_load_lds( \
    (const __attribute__((address_space(1))) void*)(g), \
    (__attribute__((address_space(3))) void*)(l), 16, 0, 0)

// Ha halo tensor: [b][f_idx 0..65][t_idx 0..513 (pad 514)][ci 0..31] bf16
#define HA_BSTRIDE 1085568  // 66*514*32

// ---------------- dtype sniffer: flag=1 means inputs are float32 ----------------
__global__ __launch_bounds__(256) void sniff_k(const u16* __restrict__ x, int* __restrict__ flag) {
    __shared__ int red[4];
    int cnt = 0;
    for (int i = 0; i < 16; ++i) {
        u16 v = x[(threadIdx.x * 16 + i) * 2];
        int e = (v >> 7) & 0xFF;
        if (e >= 110 && e <= 135) cnt++;
    }
    #pragma unroll
    for (int off = 32; off; off >>= 1) cnt += __shfl_down(cnt, off);
    if ((threadIdx.x & 63) == 0) red[threadIdx.x >> 6] = cnt;
    __syncthreads();
    if (threadIdx.x == 0) {
        int tot = red[0] + red[1] + red[2] + red[3];
        *flag = (tot < 2048) ? 1 : 0;
    }
}

__device__ __forceinline__ float ldin(const void* p, size_t i, int isf32) {
    return isf32 ? ((const float*)p)[i] : bf2f(((const u16*)p)[i]);
}

// ---------------- canonicalize all params to f32 park (one launch) ----------------
struct CvtArgs {
    const void* src[19];
    int len[19];
    int off[19];
};
__global__ __launch_bounds__(256) void cvtall_k(CvtArgs a, float* __restrict__ dst,
                                                const int* __restrict__ flag) {
    int isf32 = *flag;
    int seg = blockIdx.y;
    int n = a.len[seg];
    const void* s = a.src[seg];
    float* d = dst + a.off[seg];
    for (int i = blockIdx.x * 256 + threadIdx.x; i < n; i += gridDim.x * 256)
        d[i] = ldin(s, i, isf32);
}

// ---------------- weight transpose: W[K][N] (dual dtype) -> Wt[N][K] bf16 ----------------
__global__ __launch_bounds__(256) void wtr_k(const void* __restrict__ W, int ldw, size_t wofs,
                                             u16* __restrict__ Wt, int ldt,
                                             const int* __restrict__ flag) {
    int isf32 = *flag;
    __shared__ u16 t[64][65];
    int k0 = blockIdx.x * 64, n0 = blockIdx.y * 64;
    int tid = threadIdx.x;
    #pragma unroll
    for (int i = 0; i < 16; ++i) {
        int kk = i * 4 + (tid >> 6), nn = tid & 63;
        t[kk][nn] = f2bf(ldin(W, wofs + (size_t)(k0 + kk) * ldw + n0 + nn, isf32));
    }
    __syncthreads();
    #pragma unroll
    for (int i = 0; i < 16; ++i) {
        int nn = i * 4 + (tid >> 6), kk = tid & 63;
        Wt[(size_t)(n0 + nn) * ldt + k0 + kk] = t[kk][nn];
    }
}

// ---------------- zero / guard fill ----------------
__global__ __launch_bounds__(256) void zero_k(float4* __restrict__ p, int n4) {
    float4 z = {0.f, 0.f, 0.f, 0.f};
    for (int i = blockIdx.x * 256 + threadIdx.x; i < n4; i += gridDim.x * 256) p[i] = z;
}
__global__ __launch_bounds__(256) void fill_k(float* __restrict__ p, int n) {
    int i = blockIdx.x * 256 + threadIdx.x;
    if (i < n) p[i] = 1.0e6f;
}

// ---------------- conv stem: 1->32, k3 s2 p1 -> X f32 NCHW; 4 co per thread ----------------
__global__ __launch_bounds__(256) void conv1_k(const void* __restrict__ x, const float* __restrict__ w,
                                               const float* __restrict__ bias, float* __restrict__ out,
                                               const int* __restrict__ flag) {
    int isf32 = *flag;
    int idx = blockIdx.x * 256 + threadIdx.x;   // 4,194,304 threads
    int t  = idx & 511;
    int f  = (idx >> 9) & 63;
    int cg = (idx >> 15) & 7;       // co = cg*4 + i
    int b  = idx >> 18;
    size_t xb = (size_t)b * 128 * 1024;

    float wr[4][9];
    #pragma unroll
    for (int i = 0; i < 4; ++i)
        #pragma unroll
        for (int k = 0; k < 9; ++k) wr[i][k] = w[(cg * 4 + i) * 9 + k];

    float acc[4];
    #pragma unroll
    for (int i = 0; i < 4; ++i) acc[i] = bias[cg * 4 + i];

    #pragma unroll
    for (int df = 0; df < 3; ++df) {
        int fi = 2 * f + df - 1;
        if (fi < 0 || fi >= 128) continue;       // wave-uniform branch
        size_t rowb = xb + (size_t)fi * 1024;
        float xv[3];
        #pragma unroll
        for (int dt = 0; dt < 3; ++dt) {
            int ti = 2 * t + dt - 1;
            float v = 0.f;
            if (ti >= 0 && ti < 1024) v = ldin(x, rowb + ti, isf32);
            xv[dt] = v;
        }
        #pragma unroll
        for (int i = 0; i < 4; ++i)
            #pragma unroll
            for (int dt = 0; dt < 3; ++dt)
                acc[i] = fmaf(wr[i][df * 3 + dt], xv[dt], acc[i]);
    }
    size_t obase = (((size_t)b * 32 + cg * 4) * 64 + f) * 512 + t;
    #pragma unroll
    for (int i = 0; i < 4; ++i) out[obase + (size_t)i * 64 * 512] = acc[i];
}

// ---------------- LN-over-f stats (dual-dtype input, NCHW) ----------------
__global__ __launch_bounds__(256) void stats_k(const void* __restrict__ X, int isbf,
                                               float* __restrict__ sm, float* __restrict__ sr) {
    int idx = blockIdx.x * 256 + threadIdx.x;  // 16*32*512
    int t  = idx & 511;
    int bc = idx >> 9;
    size_t base = (size_t)bc * 64 * 512 + t;
    float s = 0.f, s2 = 0.f;
    #pragma unroll 8
    for (int f = 0; f < 64; ++f) {
        float v = isbf ? bf2f(((const u16*)X)[base + f * 512]) : ((const float*)X)[base + f * 512];
        s += v; s2 += v * v;
    }
    float m  = s * (1.f / 64.f);
    float var = fmaxf(s2 * (1.f / 64.f) - m * m, 0.f);
    sm[idx] = m;
    sr[idx] = rsqrtf(var + 1e-5f);
}

// ---------------- apply LN+ReLU: NCHW (f32|bf16) -> Ha NHWC halo bf16 ----------------
__global__ __launch_bounds__(256) void apply_k(const void* __restrict__ in, int isbf,
                                               const float* __restrict__ sm, const float* __restrict__ sr,
                                               const float* __restrict__ g, const float* __restrict__ be,
                                               u16* __restrict__ Ha) {
    int f = blockIdx.x;
    int b = blockIdx.y;
    float gg = g[f], bb_ = be[f];
    for (int it = 0; it < 2; ++it) {
        int t = it * 256 + threadIdx.x;
        u32 pk[16];
        #pragma unroll
        for (int cp = 0; cp < 16; ++cp) {
            u32 w = 0;
            #pragma unroll
            for (int half = 0; half < 2; ++half) {
                int ci = cp * 2 + half;
                size_t xi = (((size_t)b * 32 + ci) * 64 + f) * 512 + t;
                float xv = isbf ? bf2f(((const u16*)in)[xi]) : ((const float*)in)[xi];
                int si = (b * 32 + ci) * 512 + t;
                float hv = fmaxf((xv - sm[si]) * sr[si] * gg + bb_, 0.f);
                w |= ((u32)f2bf(hv)) << (half * 16);
            }
            pk[cp] = w;
        }
        u32* orow = (u32*)(Ha + (size_t)b * HA_BSTRIDE + ((size_t)(f + 1) * 514 + (t + 1)) * 32);
        #pragma unroll
        for (int q = 0; q < 16; ++q) orow[q] = pk[q];
    }
}

// ---------------- conv32 k3 s1 p1 via MFMA, GLL staging from Ha ----------------
__global__ __launch_bounds__(256) void convm_k(const u16* __restrict__ Ha, void* __restrict__ out,
                                               const float* __restrict__ w, const float* __restrict__ bias,
                                               const float* __restrict__ res) {
    __shared__ u16 act[34 * 18 * 32];  // 39168 B  [fp][tp][ci]
    int F0 = blockIdx.x * 32;
    int t0 = blockIdx.y * 16;
    int b  = blockIdx.z;
    const u16* Hb = Ha + (size_t)b * HA_BSTRIDE;
    int tid  = threadIdx.x;
    int lane = tid & 63;
    int wv   = tid >> 6;
    int quad = lane >> 4;
    int r    = lane & 15;

    #pragma unroll
    for (int it = 0; it < 10; ++it) {
        int u = it * 256 + tid;
        if (u < 2448) {
            int fp  = u / 72;           // 0..33
            int rem = u - fp * 72;
            int tp  = rem >> 2;         // 0..17
            int q   = rem & 3;
            GLL(Hb + ((size_t)(F0 + fp) * 514 + (t0 + tp)) * 32 + q * 8, act + u * 8);
        }
    }

    short8 bfrag[3][3][2];
    #pragma unroll
    for (int df = 0; df < 3; ++df)
        #pragma unroll
        for (int dt = 0; dt < 3; ++dt)
            #pragma unroll
            for (int ct = 0; ct < 2; ++ct) {
                short8 v;
                #pragma unroll
                for (int j = 0; j < 8; ++j) {
                    int co = ct * 16 + r, ci = quad * 8 + j;
                    v[j] = (short)f2bf(w[(co * 32 + ci) * 9 + df * 3 + dt]);
                }
                bfrag[df][dt][ct] = v;
            }
    __syncthreads();

    #pragma unroll
    for (int sub = 0; sub < 2; ++sub) {
        floatx4 acc[4][2];
        #pragma unroll
        for (int i = 0; i < 4; ++i)
            #pragma unroll
            for (int j = 0; j < 2; ++j)
                #pragma unroll
                for (int k = 0; k < 4; ++k) acc[i][j][k] = 0.f;

        int fb = wv * 8 + sub * 4;     // local f base, 0..28
        #pragma unroll
        for (int fh = 0; fh < 6; ++fh) {
            short8 af[3];
            #pragma unroll
            for (int dt = 0; dt < 3; ++dt)
                af[dt] = *(const short8*)&act[(((fb + fh) * 18) + (r + dt)) * 32 + quad * 8];
            #pragma unroll
            for (int df = 0; df < 3; ++df) {
                int rel = fh - df;
                if (rel < 0 || rel >= 4) continue;
                #pragma unroll
                for (int dt = 0; dt < 3; ++dt)
                    #pragma unroll
                    for (int ct = 0; ct < 2; ++ct)
                        acc[rel][ct] = __builtin_amdgcn_mfma_f32_16x16x32_bf16(
                            af[dt], bfrag[df][dt][ct], acc[rel][ct], 0, 0, 0);
            }
        }

        int tt = t0 + quad * 4;
        #pragma unroll
        for (int rel = 0; rel < 4; ++rel)
            #pragma unroll
            for (int ct = 0; ct < 2; ++ct) {
                int f  = F0 + fb + rel;
                int co = ct * 16 + r;
                size_t base = (((size_t)b * 32 + co) * 64 + f) * 512 + tt;
                float bs = bias[co];
                if (res) {
                    float4 rv = *(const float4*)(res + base);
                    float4 o;
                    o.x = acc[rel][ct][0] + bs + rv.x;
                    o.y = acc[rel][ct][1] + bs + rv.y;
                    o.z = acc[rel][ct][2] + bs + rv.z;
                    o.w = acc[rel][ct][3] + bs + rv.w;
                    *(float4*)((float*)out + base) = o;
                } else {
                    ushort4 o;
                    o.x = f2bf(acc[rel][ct][0] + bs);
                    o.y = f2bf(acc[rel][ct][1] + bs);
                    o.z = f2bf(acc[rel][ct][2] + bs);
                    o.w = f2bf(acc[rel][ct][3] + bs);
                    *(ushort4*)((u16*)out + base) = o;
                }
            }
    }
}

// ---------------- transpose X (b,c,f,t) f32 -> A[(t*16+b)][(c*64+f)] bf16 ----------------
__global__ __launch_bounds__(256) void transpose_k(const float* __restrict__ X, u16* __restrict__ A) {
    __shared__ float tile[64][65];
    int t0 = blockIdx.x * 64;
    int c  = blockIdx.y;
    int b  = blockIdx.z;
    const float* p = X + (((size_t)b * 32 + c) * 64) * 512 + t0;
    #pragma unroll
    for (int i = 0; i < 16; ++i) {
        int f = i * 4 + (threadIdx.x >> 6);
        int t = threadIdx.x & 63;
        tile[f][t] = p[(size_t)f * 512 + t];
    }
    __syncthreads();
    #pragma unroll
    for (int i = 0; i < 16; ++i) {
        int t = i * 4 + (threadIdx.x >> 6);
        int f = threadIdx.x & 63;
        A[((size_t)(t0 + t) * 16 + b) * 2048 + c * 64 + f] = f2bf(tile[f][t]);
    }
}

// ---------------- row layernorm, f32 in -> bf16 out ----------------
__global__ __launch_bounds__(256) void lnlast_k(const float* __restrict__ X, u16* __restrict__ Y,
                                                const float* __restrict__ g, const float* __restrict__ bt,
                                                int width) {
    int row = blockIdx.x;
    const float* p = X + (size_t)row * width;
    float s = 0.f, s2 = 0.f;
    for (int i = threadIdx.x; i < width; i += 256) { float v = p[i]; s += v; s2 += v * v; }
    #pragma unroll
    for (int off = 32; off; off >>= 1) { s += __shfl_down(s, off); s2 += __shfl_down(s2, off); }
    __shared__ float red[4][2];
    int wv = threadIdx.x >> 6;
    if ((threadIdx.x & 63) == 0) { red[wv][0] = s; red[wv][1] = s2; }
    __syncthreads();
    if (threadIdx.x == 0) {
        float a = 0.f, b2 = 0.f;
        for (int i = 0; i < 4; ++i) { a += red[i][0]; b2 += red[i][1]; }
        float m = a / width;
        float var = fmaxf(b2 / width - m * m, 0.f);
        red[0][0] = m; red[0][1] = rsqrtf(var + 1e-5f);
    }
    __syncthreads();
    float m = red[0][0], rs = red[0][1];
    u16* q = Y + (size_t)row * width;
    for (int i = threadIdx.x; i < width; i += 256)
        q[i] = f2bf((p[i] - m) * rs * g[i] + bt[i]);
}

// ---------------- m97-style MFMA GEMM: C = A @ Bt^T, 128x128, BK=32, GLL staging -------
// XOR k-seg swizzle: lane tid stages global seg ((tid&3)^((tid>>3)&3)) at fixed LDS slot;
// fragment reads use column (quad ^ ((r>>1)&3)) -> LDS bank spread 8-way -> 2-way (free).
__global__ __launch_bounds__(256) void gemm_bt(const u16* __restrict__ A, const u16* __restrict__ A2,
                                               int lda, const u16* __restrict__ Bt, int ldb,
                                               void* __restrict__ C, void* __restrict__ C2,
                                               int ldc, int nsplit,
                                               const float* __restrict__ bias, int relu, int K,
                                               int obf) {
    __shared__ u16 As[128 * 32];
    __shared__ u16 Bs[128 * 32];
    int tid  = threadIdx.x;
    int bm   = blockIdx.x * 128;
    int bn   = blockIdx.y * 128;
    const u16* Ab = A;
    void* Cb = C;
    int cn = bn;
    if (bn >= nsplit) { Ab = A2; Cb = C2; cn = bn - nsplit; }

    int lane = tid & 63;
    int wv   = tid >> 6;
    int quad = lane >> 4;
    int r    = lane & 15;
    int wm   = (wv >> 1) * 64;
    int wn   = (wv & 1) * 64;

    floatx4 acc[4][4];
    #pragma unroll
    for (int i = 0; i < 4; ++i)
        #pragma unroll
        for (int j = 0; j < 4; ++j)
            #pragma unroll
            for (int k = 0; k < 4; ++k) acc[i][j][k] = 0.f;

    int row0 = tid >> 2;
    int ks0  = ((tid & 3) ^ ((tid >> 3) & 3)) * 8;   // XOR swizzled k-seg
    const u16* Abase  = Ab + (size_t)(bm + row0) * lda + ks0;
    const u16* Abase2 = Ab + (size_t)(bm + 64 + row0) * lda + ks0;
    const u16* Bbase  = Bt + (size_t)(bn + row0) * ldb + ks0;
    const u16* Bbase2 = Bt + (size_t)(bn + 64 + row0) * ldb + ks0;
    u16* AsD  = As + tid * 8;
    u16* AsD2 = As + 2048 + tid * 8;
    u16* BsD  = Bs + tid * 8;
    u16* BsD2 = Bs + 2048 + tid * 8;

    for (int k0 = 0; k0 < K; k0 += 32) {
        GLL(Abase + k0, AsD);
        GLL(Abase2 + k0, AsD2);
        GLL(Bbase + k0, BsD);
        GLL(Bbase2 + k0, BsD2);
        __syncthreads();
        int col = (quad ^ ((r >> 1) & 3)) * 8;        // read-side un-swizzle
        short8 af[4], bf[4];
        #pragma unroll
        for (int mi = 0; mi < 4; ++mi) af[mi] = *(const short8*)&As[(wm + mi * 16 + r) * 32 + col];
        #pragma unroll
        for (int ni = 0; ni < 4; ++ni) bf[ni] = *(const short8*)&Bs[(wn + ni * 16 + r) * 32 + col];
        #pragma unroll
        for (int mi = 0; mi < 4; ++mi)
            #pragma unroll
            for (int ni = 0; ni < 4; ++ni)
                acc[mi][ni] = __builtin_amdgcn_mfma_f32_16x16x32_bf16(af[mi], bf[ni], acc[mi][ni], 0, 0, 0);
        __syncthreads();
    }

    #pragma unroll
    for (int mi = 0; mi < 4; ++mi)
        #pragma unroll
        for (int ni = 0; ni < 4; ++ni) {
            int col = cn + wn + ni * 16 + r;
            float bs = bias ? bias[col] : 0.f;
            #pragma unroll
            for (int reg = 0; reg < 4; ++reg) {
                int row = bm + wm + mi * 16 + quad * 4 + reg;
                float v = acc[mi][ni][reg] + bs;
                if (relu) v = fmaxf(v, 0.f);
                if (obf) ((u16*)Cb)[(size_t)row * ldc + col] = f2bf(v);
                else     ((float*)Cb)[(size_t)row * ldc + col] = v;
            }
        }
}

// ---------------- SRU scan: LDS double-buffered tile staging (m97 pattern) ----------------
#define TC 256
__global__ __launch_bounds__(128) void scan_k(const u16* __restrict__ Uf, const u16* __restrict__ Ub,
                                              const float* __restrict__ Xp, float* __restrict__ Xn,
                                              float* __restrict__ cstate, const float* __restrict__ vv,
                                              const float* __restrict__ bb, int t0f, int t0b, int init) {
    __shared__ __align__(16) char lds[2][20480];  // 16 steps * 1280 B
    int tid = threadIdx.x;
    int d   = blockIdx.x >> 6;
    int c0  = (blockIdx.x & 63) * 128;
    int b   = c0 >> 9;
    int h0  = c0 & 511;
    int h   = h0 + tid;
    int gid = d * 8192 + c0 + tid;

    float v0 = vv[(d * 2 + 0) * 512 + h];
    float v1 = vv[(d * 2 + 1) * 512 + h];
    float b0 = bb[(d * 2 + 0) * 512 + h];
    float b1 = bb[(d * 2 + 1) * 512 + h];
    const u16* U = d ? Ub : Uf;
    int t0 = d ? t0b : t0f;
    float* ob = Xn + (size_t)b * 1024 + d * 512 + h;
    float cc = init ? 0.f : cstate[gid];

    auto stage = [&](int tk, int bw) {
        #pragma unroll
        for (int it = 0; it < 10; ++it) {
            int unit = it * 128 + tid;
            int s = unit / 80;
            int j = unit - s * 80;
            int gs = tk * 16 + s;
            int sl = d ? (TC - 1 - gs) : gs;
            const void* gp;
            if (j < 48) {
                int k = j >> 4, jj = j & 15;
                gp = U + ((size_t)(sl * 16 + b) * 1536 + k * 512 + h0 + jj * 8);
            } else {
                gp = Xp + ((size_t)(t0 + sl) * 16384 + b * 1024 + d * 512 + h0 + (j - 48) * 4);
            }
            GLL(gp, &lds[bw][unit * 16]);
        }
    };

    stage(0, 0);
    __syncthreads();
    int bufw = 0;
    for (int tk = 0; tk < 16; ++tk) {
        int bufr = bufw;
        if (tk < 15) { bufw ^= 1; stage(tk + 1, bufw); }
        const char* B = lds[bufr];
        #pragma unroll
        for (int s = 0; s < 16; ++s) {
            int gs = tk * 16 + s;
            int sl = d ? (TC - 1 - gs) : gs;
            const char* sb = B + s * 1280;
            float u0 = bf2f(*(const u16*)(sb + tid * 2));
            float fp = bf2f(*(const u16*)(sb + 256 + tid * 2)) + b0;
            float rp = bf2f(*(const u16*)(sb + 512 + tid * 2)) + b1;
            float xr = *(const float*)(sb + 768 + tid * 4);
            float f = 1.f / (1.f + __expf(-(fp + v0 * cc)));
            float r = 1.f / (1.f + __expf(-(rp + v1 * cc)));
            cc = f * cc + (1.f - f) * u0;
            float th = 1.f - 2.f / (__expf(2.f * cc) + 1.f);
            ob[(size_t)(t0 + sl) * 16384] = r * th + (1.f - r) * xr;
        }
        __syncthreads();
    }
    cstate[gid] = cc;
}

// ---------------- classifier head ----------------
__global__ __launch_bounds__(256) void cls2_k(const float* __restrict__ FC1, const float* __restrict__ W2,
                                              const float* __restrict__ b2, void* __restrict__ out,
                                              const int* __restrict__ flag) {
    int isf32 = *flag;
    int row = blockIdx.x * 4 + (threadIdx.x >> 6);
    int v   = threadIdx.x & 63;
    if (v >= 29) return;
    const float* p = FC1 + (size_t)row * 512;
    float acc = 0.f;
    for (int k = 0; k < 512; ++k) acc = fmaf(p[k], W2[k * 29 + v], acc);
    acc += b2[v];
    int t = row >> 4, b = row & 15;
    size_t oi = ((size_t)b * 512 + t) * 29 + v;
    if (isf32) ((float*)out)[oi] = acc;
    else       ((u16*)out)[oi]   = f2bf(acc);
}

// ---------------- launch ----------------
extern "C" void kernel_launch(void* const* d_in, const int* in_sizes, int n_in,
                              void* d_out, int out_size, void* d_ws, size_t ws_size,
                              hipStream_t stream) {
    const void* x      = d_in[0];
    const void* proj_w = d_in[11];
    const void* sru_w  = d_in[12];
    const void* cls_w1 = d_in[19];

    float* ws = (float*)d_ws;
    const size_t O_X    = 0;
    const size_t O_C    = 16777216;
    const size_t O_HA   = 25165824;
    const size_t O_SM   = 33850368;
    const size_t O_SR   = 34112512;
    const size_t O_CST  = 34374656;
    const size_t O_PARK = 34391040;
    const size_t O_FLAG = 34483488;
    const size_t TOTAL  = 34483504;   // 131.55 MiB
    if (ws_size < TOTAL * sizeof(float)) {
        fill_k<<<(out_size + 255) / 256, 256, 0, stream>>>((float*)d_out, out_size);
        return;
    }

    float* X   = ws + O_X;
    u16*   C   = (u16*)(ws + O_C);
    u16*   HA  = (u16*)(ws + O_HA);
    float* SM  = ws + O_SM;
    float* SR  = ws + O_SR;
    float* CST = ws + O_CST;
    float* PK  = ws + O_PARK;
    int*   FLG = (int*)(ws + O_FLAG);

    u16*   Abf = (u16*)(ws + O_C);
    u16*   BtP = (u16*)(ws + 0);
    float* XP0 = ws + 25165824;
    u16*   XL  = (u16*)(ws + 0);
    float* XP1 = ws + 4194304;
    u16*   Uf  = (u16*)(ws + 12582912);
    u16*   Ub  = (u16*)(ws + 15728640);
    u16*   BtS = (u16*)(ws + 18874368);
    u16*   BtC = (u16*)(ws + O_SM);
    float* FC1 = ws + 12582912;

    float* p_cnn_w = PK + 0;      float* p_cnn_b = PK + 288;
    float* p_rw1   = PK + 320;    float* p_rb1   = PK + 27968;
    float* p_rw2   = PK + 28064;  float* p_rb2   = PK + 55712;
    float* p_l1g   = PK + 55808;  float* p_l1b   = PK + 56000;
    float* p_l2g   = PK + 56192;  float* p_l2b   = PK + 56384;
    float* p_sv    = PK + 56576;  float* p_sb    = PK + 62720;
    float* p_slng  = PK + 68864;  float* p_slnb  = PK + 71936;
    float* p_clng  = PK + 75008;  float* p_clnb  = PK + 76032;
    float* p_cb1   = PK + 77056;  float* p_cw2   = PK + 77568;
    float* p_cb2   = PK + 92416;

    sniff_k<<<1, 256, 0, stream>>>((const u16*)x, FLG);

    CvtArgs ca;
    const int srcidx[19] = {1,2,3,4,5,6,7,8,9,10,13,14,15,16,17,18,20,21,22};
    const int lens[19]   = {288,32,27648,96,27648,96,192,192,192,192,6144,6144,3072,3072,1024,1024,512,14848,29};
    const int offs[19]   = {0,288,320,27968,28064,55712,55808,56000,56192,56384,56576,62720,68864,71936,75008,76032,77056,77568,92416};
    for (int i = 0; i < 19; ++i) { ca.src[i] = d_in[srcidx[i]]; ca.len[i] = lens[i]; ca.off[i] = offs[i]; }
    cvtall_k<<<dim3(108, 19), 256, 0, stream>>>(ca, PK, FLG);

    zero_k<<<2048, 256, 0, stream>>>((float4*)HA, 2171136);
    conv1_k<<<16384, 256, 0, stream>>>(x, p_cnn_w, p_cnn_b, X, FLG);

    for (int i = 0; i < 3; ++i) {
        stats_k<<<1024, 256, 0, stream>>>(X, 0, SM, SR);
        apply_k<<<dim3(64, 16), 256, 0, stream>>>(X, 0, SM, SR, p_l1g + i * 64, p_l1b + i * 64, HA);
        convm_k<<<dim3(2, 32, 16), 256, 0, stream>>>(HA, C, p_rw1 + i * 9216, p_rb1 + i * 32, nullptr);
        stats_k<<<1024, 256, 0, stream>>>(C, 1, SM, SR);
        apply_k<<<dim3(64, 16), 256, 0, stream>>>(C, 1, SM, SR, p_l2g + i * 64, p_l2b + i * 64, HA);
        convm_k<<<dim3(2, 32, 16), 256, 0, stream>>>(HA, X, p_rw2 + i * 9216, p_rb2 + i * 32, X);
    }

    transpose_k<<<dim3(8, 32, 16), 256, 0, stream>>>(X, Abf);
    wtr_k<<<dim3(32, 16), 256, 0, stream>>>(proj_w, 1024, 0, BtP, 2048, FLG);
    gemm_bt<<<dim3(64, 8), 256, 0, stream>>>(Abf, Abf, 2048, BtP, 2048, XP0, XP0, 1024,
                                             1 << 30, nullptr, 0, 2048, 0);

    for (int l = 0; l < 3; ++l)
        wtr_k<<<dim3(16, 48), 256, 0, stream>>>(sru_w, 3072, (size_t)l * 3145728,
                                                BtS + (size_t)l * 3145728, 1024, FLG);
    wtr_k<<<dim3(16, 8), 256, 0, stream>>>(cls_w1, 512, 0, BtC, 1024, FLG);

    float* cur = XP0;
    float* nxt = XP1;
    for (int l = 0; l < 3; ++l) {
        lnlast_k<<<8192, 256, 0, stream>>>(cur, XL, p_slng + l * 1024, p_slnb + l * 1024, 1024);
        const u16* Btl = BtS + (size_t)l * 3145728;
        for (int j = 0; j < 2; ++j) {
            int t0f = j * TC;
            int t0b = (1 - j) * TC;
            gemm_bt<<<dim3(32, 24), 256, 0, stream>>>(XL + (size_t)t0f * 16 * 1024,
                                                      XL + (size_t)t0b * 16 * 1024, 1024,
                                                      Btl, 1024, Uf, Ub, 1536, 1536,
                                                      nullptr, 0, 1024, 1);
            scan_k<<<128, 128, 0, stream>>>(Uf, Ub, cur, nxt, CST,
                                            p_sv + l * 2048, p_sb + l * 2048, t0f, t0b, j == 0);
        }
        float* tmp = cur; cur = nxt; nxt = tmp;
    }

    lnlast_k<<<8192, 256, 0, stream>>>(cur, XL, p_clng, p_clnb, 1024);
    gemm_bt<<<dim3(64, 4), 256, 0, stream>>>(XL, XL, 1024, BtC, 1024, FC1, FC1, 512,
                                             1 << 30, p_cb1, 1, 1024, 0);
    cls2_k<<<2048, 256, 0, stream>>>(FC1, p_cw2, p_cb2, d_out, FLG);
}